// Round 8
// baseline (567.640 us; speedup 1.0000x reference)
//
#include <hip/hip_runtime.h>
#include <stdint.h>

#define TT   12
#define BB   2
#define NN   1024
#define MM   2048
#define TM   24576      // TT*MM
#define DIN  64
#define DH   128
#define DOUT 32
#define CAP  64
#define OUTSZ 786432
#define PWB  292        // prepw blocks (74528 items / 256) inside k_pex

typedef __attribute__((ext_vector_type(8))) short short8;
typedef __attribute__((ext_vector_type(4))) short short4v;
typedef __attribute__((ext_vector_type(4))) float f32x4;

#define MFMA(a,b,c) __builtin_amdgcn_mfma_f32_16x16x32_bf16((a),(b),(c),0,0,0)

__device__ __forceinline__ float bf2f(unsigned short u){
  union { uint32_t i; float f; } x; x.i = ((uint32_t)u) << 16; return x.f;
}
__device__ __forceinline__ unsigned short f2bf(float f){
  union { float f; uint32_t i; } x; x.f = f;
  uint32_t u = x.i + 0x7FFFu + ((x.i >> 16) & 1u);   // RNE
  return (unsigned short)(u >> 16);
}
__device__ __forceinline__ float LD(const void* p, size_t i, int mode){
  return mode ? ((const float*)p)[i] : bf2f(((const unsigned short*)p)[i]);
}
// gather-load 8 input elements as bf16 (mode 1 = fp32 source)
__device__ __forceinline__ short8 ldx8(const void* x, size_t off, int md){
  if(md){
    const float4* xf = (const float4*)((const float*)x + off);
    float4 a = xf[0], b = xf[1];
    short8 o;
    o[0]=(short)f2bf(a.x); o[1]=(short)f2bf(a.y); o[2]=(short)f2bf(a.z); o[3]=(short)f2bf(a.w);
    o[4]=(short)f2bf(b.x); o[5]=(short)f2bf(b.y); o[6]=(short)f2bf(b.z); o[7]=(short)f2bf(b.w);
    return o;
  }
  return *(const short8*)((const unsigned short*)x + off);
}

// ---------------- fill (fp32, sentinels only) ----------------
__global__ void k_fill(float* __restrict__ out, int n, float val){
  int i = blockIdx.x*blockDim.x + threadIdx.x;
  if(i < n) out[i] = val;
}

// ---------------- L1: mask decode + x-dtype detect (13 blocks) ----------------
// Blocks 0..TT-1: per-block redundant mask-dtype detect (24KB eg scan, L2) then
// LDS-prefix compaction of timestep t (deterministic, no global atomics).
// Block TT: x dtype detect -> dtf. Out-zeroing moved into k_attn (disjoint writes).
__global__ __launch_bounds__(256) void k_maskdet(
    const void* __restrict__ egom, const unsigned short* __restrict__ xs,
    int* __restrict__ dtf,
    int* __restrict__ cnt, int* __restrict__ nact,
    int* __restrict__ aidx, int* __restrict__ inv)
{
  const int bid = blockIdx.x, tid = threadIdx.x;
  if(bid == TT){                             // x dtype detect
    __shared__ int cnt_s;
    if(tid == 0) cnt_s = 0;
    __syncthreads();
    int c = 0;
    for(int i = tid; i < 6144; i += 256){
      unsigned short hh = xs[i*2];
      unsigned e = (hh >> 7) & 0xFF;
      if(hh==0 || (e >= 0x60 && e <= 0x9F)) c++;
    }
    if(c) atomicAdd(&cnt_s, c);
    __syncthreads();
    if(tid == 0) *dtf = (cnt_s > 4000) ? 0 : 1;   // 0=bf16, 1=fp32
    return;
  }
  const int t = bid, lane = tid & 63, wv = tid >> 6;

  __shared__ int pres_s, ge2_s, wcnt_s[4];
  if(tid == 0){ pres_s = 0; ge2_s = 0; }
  __syncthreads();
  {
    int pres = 0, ge2 = 0;
    const unsigned char* egp = (const unsigned char*)egom;
    for(int i = tid; i < 24576; i += 256){
      unsigned v = egp[i];
      if(v){ pres |= 1 << (i & 7); if(v >= 2u) ge2 = 1; }
    }
    if(pres) atomicOr(&pres_s, pres);
    if(ge2)  atomicOr(&ge2_s, 1);
  }
  __syncthreads();
  int mode;
  {
    int pr = pres_s, g2 = ge2_s;
    if(!g2){
      if((pr & ~0x01) == 0)      mode = 4;   // i64
      else if((pr & ~0x11) == 0) mode = 0;   // i32
      else                       mode = 1;   // u8
    } else {
      if((pr & ~0xC0) == 0)      mode = 5;   // f64
      else if((pr & ~0xCC) == 0) mode = 3;   // f32
      else                       mode = 2;   // bf16
    }
  }

  int base = 0;                              // uniform running prefix (register)
  for(int r = 0; r < 8; r++){
    int node = r*256 + tid;
    int b = node / NN, n = node % NN;
    int src = (b*TT + t)*NN + n;
    int v;
    if(mode==0)      v = ((const int*)egom)[src] != 0;
    else if(mode==1) v = ((const unsigned char*)egom)[src] != 0;
    else if(mode==2) v = ((const unsigned short*)egom)[src] != 0;
    else if(mode==3) v = ((const float*)egom)[src] != 0.f;
    else if(mode==4) v = ((const long long*)egom)[src] != 0;
    else             v = ((const double*)egom)[src] != 0.0;
    cnt[(size_t)t*MM + node] = 0;
    unsigned long long bal = __ballot(v != 0);
    if(lane == 0) wcnt_s[wv] = __popcll(bal);
    __syncthreads();
    int mybase = base;
    for(int w2 = 0; w2 < wv; w2++) mybase += wcnt_s[w2];
    int ic = -1;
    if(v){
      ic = mybase + __popcll(bal & ((1ULL << lane) - 1ULL));
      aidx[(size_t)t*MM + ic] = node;
    }
    inv[(size_t)t*MM + node] = ic;
    base += wcnt_s[0] + wcnt_s[1] + wcnt_s[2] + wcnt_s[3];
    __syncthreads();                        // protect wcnt_s before next round
  }
  if(tid == 0) nact[t] = base;
}

// ================= device bodies =================

// weight prep WITHOUT the W1t segment (gemm_x reads w1 directly). 74528 items.
__device__ __forceinline__ void dev_prepw2_item(int id, int md,
  const void* w2,
  const void* qw, const void* kw, const void* vw,
  const void* qb0, const void* kb0, const void* vb0,
  const void* ow, const void* ob, const void* fw, const void* fb,
  const void* tw, const void* tb, const void* b1, const void* b2,
  unsigned short* W2t,
  unsigned short* Wqt, unsigned short* Wkt,
  unsigned short* Wvt, unsigned short* Wct,
  float* qbf, float* kbf, float* vbf,
  float* bcf, float* b1f, float* b2f)
{
  if(id < 16384){ int n=id&127,k2=id>>7; W2t[n*128+k2]=f2bf(LD(w2,(size_t)k2*128+n,md)); return; }
  id -= 16384;
  if(id < 16384){ int n=id&127,k2=id>>7; Wqt[n*128+k2]=f2bf(LD(qw,(size_t)k2*128+n,md)); return; }
  id -= 16384;
  if(id < 16384){ int n=id&127,k2=id>>7; Wkt[n*128+k2]=f2bf(LD(kw,(size_t)k2*128+n,md)); return; }
  id -= 16384;
  if(id < 16384){ int n=id&127,k2=id>>7; Wvt[n*128+k2]=f2bf(LD(vw,(size_t)k2*128+n,md)); return; }
  id -= 16384;
  if(id < 4096){  // Wc = o_w @ fc_w, stored [oc][c]
    int oc=id&31, c=id>>5; float s=0.f;
    for(int r=0;r<128;r++) s += LD(ow,(size_t)c*128+r,md)*LD(fw,(size_t)r*32+oc,md);
    Wct[oc*128+c]=f2bf(s); return;
  }
  id -= 4096;
  if(id < 32){    // bc = o_b @ fc_w + fc_b
    float s = LD(fb,id,md);
    for(int r=0;r<128;r++) s += LD(ob,r,md)*LD(fw,(size_t)r*32+id,md);
    bcf[id]=s; return;
  }
  id -= 32;
  if(id < 4608){  // per-t fused QKV bias: b + t_vec @ W[128:144]
    int which = id/1536, rem=id%1536, t=rem/128, n=rem%128;
    const void* W  = which==0?qw:(which==1?kw:vw);
    const void* Bs = which==0?qb0:(which==1?kb0:vb0);
    float s = LD(Bs,n,md);
    for(int d=0;d<16;d++){
      float tv = sinf((float)t*LD(tw,d,md) + LD(tb,d,md));
      s += tv * LD(W,(size_t)(128+d)*128+n,md);
    }
    float* dst = which==0?qbf:(which==1?kbf:vbf);
    dst[t*128+n]=s; return;
  }
  id -= 4608;
  if(id < 256){   // GCN biases to fp32
    if(id<128) b1f[id] = LD(b1,id,md);
    else       b2f[id-128] = LD(b2,id-128,md);
    return;
  }
}

// COALESCED edge scan: one wave per row, lane i + iter u reads vector index
// u*64+i -> consecutive lanes touch consecutive 16B (1KB/wave-instruction).
__device__ __forceinline__ void dev_edges_item(int id, int md,
    const void* A, const int* inv, int* cnt, int* edges){
  int lane = id & 63; int row = id >> 6;          // row = t*MM + j (orig)
  int t = row / MM;
  int jc = inv[row];
  if(jc < 0) return;                              // inactive source
  const int* invt = inv + (size_t)t*MM;
  int* cb = cnt + (size_t)t*MM;
  int* eb = edges + (size_t)t*MM*CAP;
  if(md){   // fp32 adjacency: 512 float4 per row
    const float4* p4 = (const float4*)((const float*)A + (size_t)row*MM);
    #pragma unroll
    for(int u=0;u<8;u++){
      float4 v = p4[u*64 + lane];
      float wd[4]={v.x,v.y,v.z,v.w};
      #pragma unroll
      for(int q=0;q<4;q++){
        if(wd[q]!=0.f){
          int ibc = invt[(u*64 + lane)*4 + q];
          if(ibc >= 0){ int s=atomicAdd(&cb[ibc],1); if(s<CAP) eb[(size_t)ibc*CAP+s]=jc; }
        }
      }
    }
  } else {    // bf16 adjacency: 256 uint4 per row (8 bf16 each)
    const uint4* p4 = (const uint4*)((const unsigned short*)A + (size_t)row*MM);
    #pragma unroll
    for(int u=0;u<4;u++){
      uint4 v = p4[u*64 + lane];
      unsigned wd[4]={v.x,v.y,v.z,v.w};
      #pragma unroll
      for(int q=0;q<4;q++){
        int ib = (u*64 + lane)*8 + q*2;
        if(wd[q] & 0xFFFFu){
          int ibc = invt[ib];
          if(ibc >= 0){ int s=atomicAdd(&cb[ibc],1); if(s<CAP) eb[(size_t)ibc*CAP+s]=jc; }
        }
        if(wd[q] >> 16){
          int ibc = invt[ib+1];
          if(ibc >= 0){ int s=atomicAdd(&cb[ibc],1); if(s<CAP) eb[(size_t)ibc*CAP+s]=jc; }
        }
      }
    }
  }
}

// gemm_x reading w1 DIRECTLY (transposed access; w1 is 32KB, L2-hot)
__device__ __forceinline__ void dev_gemm_x_direct(int tileIdx, int md, int tid,
    const void* x, const int* nact, const int* aidx,
    const void* w1, float* g)
{
  const int tile = tileIdx*64;
  const int t = tile / MM, il = tile % MM;
  const int na = nact[t];
  if(il >= ((na+63)&~63)) return;
  const int wv=tid>>6, lane=tid&63, l15=lane&15, quad=lane>>4;
  const int r0 = tile + (wv>>1)*32;          // global compact row base
  const int c0 = (wv&1)*64;
  short8 bf[2][4];
  #pragma unroll
  for(int kk=0;kk<2;kk++)
    #pragma unroll
    for(int nt=0;nt<4;nt++){
      const int col = c0+nt*16+l15;
      short8 o;
      #pragma unroll
      for(int j=0;j<8;j++)
        o[j] = (short)f2bf(LD(w1, (size_t)(kk*32 + quad*8 + j)*DH + col, md));
      bf[kk][nt] = o;
    }
  const int il0 = (r0 % MM) + l15, il1 = (r0 % MM) + 16 + l15;
  const int n0 = aidx[(size_t)t*MM + (il0 < na ? il0 : 0)];
  const int n1 = aidx[(size_t)t*MM + (il1 < na ? il1 : 0)];
  const size_t xb0 = ((size_t)t*MM + n0)*DIN;
  const size_t xb1 = ((size_t)t*MM + n1)*DIN;
  f32x4 z = {0.f,0.f,0.f,0.f};
  f32x4 acc[2][4];
  #pragma unroll
  for(int i=0;i<2;i++){ acc[i][0]=z; acc[i][1]=z; acc[i][2]=z; acc[i][3]=z; }
  #pragma unroll
  for(int kk=0;kk<2;kk++){
    short8 a0 = ldx8(x, xb0 + kk*32 + quad*8, md);
    short8 a1 = ldx8(x, xb1 + kk*32 + quad*8, md);
    #pragma unroll
    for(int nt=0;nt<4;nt++){
      acc[0][nt]=MFMA(a0,bf[kk][nt],acc[0][nt]);
      acc[1][nt]=MFMA(a1,bf[kk][nt],acc[1][nt]);
    }
  }
  #pragma unroll
  for(int mt=0;mt<2;mt++)
    #pragma unroll
    for(int nt=0;nt<4;nt++){
      int col = c0+nt*16+l15;
      #pragma unroll
      for(int r=0;r<4;r++){
        int row = r0 + mt*16 + quad*4 + r;
        g[(size_t)row*DH + col] = acc[mt][nt][r];
      }
    }
}

// ---------------- L2: prepw + edges + gemm_x in one launch ----------------
__global__ __launch_bounds__(256) void k_pex(
  const void* __restrict__ x, const void* __restrict__ A,
  const void* __restrict__ w1, const void* __restrict__ w2,
  const void* __restrict__ qw, const void* __restrict__ kw, const void* __restrict__ vw,
  const void* __restrict__ qb0, const void* __restrict__ kb0, const void* __restrict__ vb0,
  const void* __restrict__ ow, const void* __restrict__ ob,
  const void* __restrict__ fw, const void* __restrict__ fb,
  const void* __restrict__ tw, const void* __restrict__ tb,
  const void* __restrict__ b1, const void* __restrict__ b2,
  const int* __restrict__ dtf,
  const int* __restrict__ inv, int* __restrict__ cnt, int* __restrict__ edges,
  const int* __restrict__ nact, const int* __restrict__ aidx, float* __restrict__ g,
  unsigned short* __restrict__ W2t,
  unsigned short* __restrict__ Wqt, unsigned short* __restrict__ Wkt,
  unsigned short* __restrict__ Wvt, unsigned short* __restrict__ Wct,
  float* __restrict__ qbf, float* __restrict__ kbf, float* __restrict__ vbf,
  float* __restrict__ bcf, float* __restrict__ b1f, float* __restrict__ b2f)
{
  const int tid = threadIdx.x;
  const int md = *dtf;                       // produced by k_maskdet block TT
  const int b = blockIdx.x;
  if(b < PWB){
    dev_prepw2_item(b*256 + tid, md, w2, qw,kw,vw, qb0,kb0,vb0, ow,ob,fw,fb, tw,tb, b1,b2,
                    W2t, Wqt, Wkt, Wvt, Wct, qbf, kbf, vbf, bcf, b1f, b2f);
  } else if(b < PWB + TM*64/256){
    dev_edges_item((b - PWB)*256 + tid, md, A, inv, cnt, edges);
  } else {
    dev_gemm_x_direct(b - PWB - TM*64/256, md, tid, x, nact, aidx, w1, g);
  }
}

// ---- shared fused-gather phase: 64 compact rows of timestep t -> Hl (bf16) ----
// Each wave handles 16 rows sequentially; per-row edge chains are independent
// loads (unroll 4 for MLP). Pad rows (ic>=na) get zeros.
__device__ __forceinline__ void dev_gather_tile(int tile, int t, int il, int na,
    int tid, const float* __restrict__ gsrc, const int* __restrict__ edges,
    const int* __restrict__ cnt, const float* __restrict__ bias,
    unsigned short (*Hl)[136])
{
  const int wv = tid>>6, lane = tid&63;
  for(int r = 0; r < 16; r++){
    const int lrow = wv*16 + r;
    const int ic = il + lrow;
    const int gi = t*MM + ic;
    float h0 = 0.f, h1 = 0.f;
    if(ic < na){
      float a0=0.f, a1=0.f;
      int cn = cnt[gi]; if(cn>CAP) cn=CAP;
      const int* eb = edges + (size_t)gi*CAP;
      #pragma unroll 4
      for(int e=0;e<cn;e++){
        int jc = eb[e];
        float nj = rsqrtf((float)cnt[(size_t)t*MM+jc] + 1.f);
        float2 gr2 = *(const float2*)(gsrc + ((size_t)t*MM + jc)*DH + 2*lane);
        a0 += nj*gr2.x; a1 += nj*gr2.y;
      }
      float ni = rsqrtf((float)cn + 1.f);
      float2 gs2 = *(const float2*)(gsrc + (size_t)gi*DH + 2*lane);
      h0 = ni*(a0 + ni*gs2.x) + bias[2*lane];
      h1 = ni*(a1 + ni*gs2.y) + bias[2*lane+1];
      h0 = h0>0.f?h0:0.f; h1 = h1>0.f?h1:0.f;
    }
    *(unsigned int*)&Hl[lrow][2*lane] =
        (unsigned int)f2bf(h0) | ((unsigned int)f2bf(h1) << 16);
  }
}

// ---------------- L3: fused gather1 + gemm_h  (g -> Hl -> g2) ----------------
// Writes to a SEPARATE buffer g2: writing g would race with other blocks'
// neighbor-gathers still reading g (round-4 lesson).
__global__ __launch_bounds__(256) void k_gg1(
    const float* __restrict__ g, const int* __restrict__ edges,
    const int* __restrict__ cnt, const int* __restrict__ nact,
    const float* __restrict__ bias, const unsigned short* __restrict__ Wt,
    float* __restrict__ g2)
{
  __shared__ unsigned short Hl[64][136];    // padded: 2-way bank aliasing only
  const int tid = threadIdx.x, wv = tid>>6, lane = tid&63, l15 = lane&15, quad = lane>>4;
  const int tile = blockIdx.x*64;
  const int t = tile / MM, il = tile % MM;
  const int na = nact[t];
  if(il >= ((na+63)&~63)) return;

  dev_gather_tile(tile, t, il, na, tid, g, edges, cnt, bias, Hl);
  __syncthreads();

  const int r0l = (wv>>1)*32;               // local row base within tile
  const int c0 = (wv&1)*64;
  short8 bf[4][4];
  #pragma unroll
  for(int kk=0;kk<4;kk++)
    #pragma unroll
    for(int nt=0;nt<4;nt++)
      bf[kk][nt] = *(const short8*)(Wt + (size_t)(c0+nt*16+l15)*DH + kk*32 + quad*8);
  f32x4 z = {0.f,0.f,0.f,0.f};
  f32x4 acc[2][4];
  #pragma unroll
  for(int i=0;i<2;i++){ acc[i][0]=z; acc[i][1]=z; acc[i][2]=z; acc[i][3]=z; }
  #pragma unroll
  for(int kk=0;kk<4;kk++){
    short8 a0 = *(const short8*)&Hl[r0l+l15   ][kk*32 + quad*8];
    short8 a1 = *(const short8*)&Hl[r0l+16+l15][kk*32 + quad*8];
    #pragma unroll
    for(int nt=0;nt<4;nt++){
      acc[0][nt]=MFMA(a0,bf[kk][nt],acc[0][nt]);
      acc[1][nt]=MFMA(a1,bf[kk][nt],acc[1][nt]);
    }
  }
  #pragma unroll
  for(int mt=0;mt<2;mt++)
    #pragma unroll
    for(int nt=0;nt<4;nt++){
      int col = c0+nt*16+l15;
      #pragma unroll
      for(int r=0;r<4;r++){
        int row = tile + r0l + mt*16 + quad*4 + r;
        g2[(size_t)row*DH + col] = acc[mt][nt][r];
      }
    }
}

// ---------------- L4: fused gather2 + Q/K/V GEMMs  (g2 -> Hl -> Q,K,Vt) ----------------
__global__ __launch_bounds__(256) void k_gqkv(
    const float* __restrict__ g2, const int* __restrict__ edges,
    const int* __restrict__ cnt, const int* __restrict__ nact,
    const float* __restrict__ bias2,
    const unsigned short* __restrict__ Wq, const unsigned short* __restrict__ Wk,
    const unsigned short* __restrict__ Wv,
    const float* __restrict__ qb, const float* __restrict__ kb, const float* __restrict__ vb,
    unsigned short* __restrict__ Qo, unsigned short* __restrict__ Ko,
    unsigned short* __restrict__ Vtc)
{
  __shared__ unsigned short Hl[64][136];
  const int tid = threadIdx.x, wv = tid>>6, lane = tid&63, l15 = lane&15, quad = lane>>4;
  const int tile = blockIdx.x*64;
  const int t = tile / MM, il = tile % MM;
  const int na = nact[t];
  if(il >= ((na+63)&~63)) return;

  dev_gather_tile(tile, t, il, na, tid, g2, edges, cnt, bias2, Hl);
  __syncthreads();

  const int r0l = (wv>>1)*32;
  const int c0 = (wv&1)*64;
  f32x4 z = {0.f,0.f,0.f,0.f};
  for(int which = 0; which < 3; which++){
    const unsigned short* Wt = which==0?Wq:(which==1?Wk:Wv);
    const float* bias = which==0?qb:(which==1?kb:vb);
    short8 bf[4][4];
    #pragma unroll
    for(int kk=0;kk<4;kk++)
      #pragma unroll
      for(int nt=0;nt<4;nt++)
        bf[kk][nt] = *(const short8*)(Wt + (size_t)(c0+nt*16+l15)*DH + kk*32 + quad*8);
    f32x4 acc[2][4];
    #pragma unroll
    for(int i=0;i<2;i++){ acc[i][0]=z; acc[i][1]=z; acc[i][2]=z; acc[i][3]=z; }
    #pragma unroll
    for(int kk=0;kk<4;kk++){
      short8 a0 = *(const short8*)&Hl[r0l+l15   ][kk*32 + quad*8];
      short8 a1 = *(const short8*)&Hl[r0l+16+l15][kk*32 + quad*8];
      #pragma unroll
      for(int nt=0;nt<4;nt++){
        acc[0][nt]=MFMA(a0,bf[kk][nt],acc[0][nt]);
        acc[1][nt]=MFMA(a1,bf[kk][nt],acc[1][nt]);
      }
    }
    if(which < 2){
      unsigned short* o = which==0 ? Qo : Ko;
      #pragma unroll
      for(int mt=0;mt<2;mt++)
        #pragma unroll
        for(int nt=0;nt<4;nt++){
          int col = c0+nt*16+l15;
          float bb = bias[t*DH+col];
          #pragma unroll
          for(int r=0;r<4;r++){
            int row = tile + r0l + mt*16 + quad*4 + r;
            o[(size_t)row*DH + col] = f2bf(acc[mt][nt][r] + bb);
          }
        }
    } else {
      #pragma unroll
      for(int mt=0;mt<2;mt++)
        #pragma unroll
        for(int nt=0;nt<4;nt++){
          int col = c0+nt*16+l15;
          float bb = bias[t*DH+col];
          int node0 = il + r0l + mt*16 + quad*4;   // compact local row
          short4v pk;
          #pragma unroll
          for(int r=0;r<4;r++) pk[r] = (short)f2bf(acc[mt][nt][r] + bb);
          *(short4v*)(Vtc + ((size_t)t*DH + col)*MM + node0) = pk;
        }
    }
  }
}

// ---------------- L5: fused attention + concurrent inactive-node zeroing ----------------
__global__ __launch_bounds__(256) void k_attn(
  const unsigned short* __restrict__ Q, const unsigned short* __restrict__ Kc,
  const unsigned short* __restrict__ Vtc, const int* __restrict__ nact,
  const int* __restrict__ aidx, const int* __restrict__ inv,
  const unsigned short* __restrict__ Wct,
  const float* __restrict__ bc, float* __restrict__ out)
{
  __shared__ unsigned short Kl[64][136];   // 64 keys x 128ch
  __shared__ unsigned short Vl[128][72];   // 128 ch x 64 keys
  __shared__ short Pl[4][16][72];          // per-wave P tile
  __shared__ short Al[4][16][136];         // per-wave accumulator (bf16) for projection
  const int tid=threadIdx.x, wv=tid>>6, lane=tid&63, l15=lane&15, quad=lane>>4;
  const int t = blockIdx.y;
  const int na = nact[t];
  const int qblk = blockIdx.x*64;

  // zero out-slices of INACTIVE nodes in this block's node range; disjoint from
  // the projection writes (active nodes only) -> no ordering needed.
  {
    int nd = blockIdx.x*64 + (tid >> 2);           // 64 nodes, 4 threads each
    if(inv[(size_t)t*MM + nd] < 0){
      f32x4 z4 = {0.f,0.f,0.f,0.f};
      f32x4* op = (f32x4*)(out + (size_t)nd*(TT*DOUT) + (size_t)t*DOUT);
      op[(tid&3)*2]   = z4;
      op[(tid&3)*2+1] = z4;
    }
  }
  if(qblk >= na) return;                 // block-uniform exit (before any barrier)
  const int qbase = qblk + wv*16;
  const float scale = 0.088388347648318447f;  // 1/sqrt(128)
  const int nkt = (na + 63) >> 6;

  short8 bq[4];
  #pragma unroll
  for(int kk=0;kk<4;kk++)
    bq[kk] = *(const short8*)(Q + ((size_t)t*MM + qbase + l15)*DH + kk*32 + quad*8);

  f32x4 zz = {0.f,0.f,0.f,0.f};
  f32x4 accPV[8];
  #pragma unroll
  for(int i=0;i<8;i++) accPV[i]=zz;
  float l_run = 0.f;

  const int srow = tid >> 2, sseg = tid & 3;   // K stage: 64 rows x 4 segs
  const int vch  = tid >> 1, vhalf = tid & 1;  // V stage: 128 ch x 2 halves

  short8 kreg[4], vreg[4];
  {  // preload tile 0 into registers
    const unsigned short* gk = Kc + ((size_t)t*MM + srow)*DH + sseg*32;
    const unsigned short* gv = Vtc + ((size_t)t*DH + vch)*MM + vhalf*32;
    #pragma unroll
    for(int j=0;j<4;j++){ kreg[j] = *(const short8*)(gk + j*8);
                          vreg[j] = *(const short8*)(gv + j*8); }
  }

  for(int kt=0; kt<nkt; kt++){
    const int key0 = kt*64;
    __syncthreads();   // previous tile fully consumed before restage
    {  // write prefetched registers to LDS
      short8* kd = (short8*)&Kl[srow][sseg*32];
      short8* vd = (short8*)&Vl[vch][vhalf*32];
      #pragma unroll
      for(int j=0;j<4;j++){ kd[j] = kreg[j]; vd[j] = vreg[j]; }
    }
    __syncthreads();
    if(kt+1 < nkt){   // issue next tile's global loads; they overlap compute below
      const int key1 = key0 + 64;
      const unsigned short* gk = Kc + ((size_t)t*MM + key1 + srow)*DH + sseg*32;
      const unsigned short* gv = Vtc + ((size_t)t*DH + vch)*MM + key1 + vhalf*32;
      #pragma unroll
      for(int j=0;j<4;j++){ kreg[j] = *(const short8*)(gk + j*8);
                            vreg[j] = *(const short8*)(gv + j*8); }
    }
    // S^T = K · Q^T from LDS
    #pragma unroll
    for(int mt=0;mt<4;mt++){
      f32x4 s = zz;
      #pragma unroll
      for(int kk=0;kk<4;kk++){
        short8 ak = *(const short8*)&Kl[mt*16+l15][kk*32 + quad*8];
        s = MFMA(ak, bq[kk], s);
      }
      short4v pk;
      #pragma unroll
      for(int r=0;r<4;r++){
        float sv = fminf(fmaxf(s[r]*scale, -15.f), 15.f);
        float valid = (key0 + mt*16 + quad*4 + r < na) ? 1.f : 0.f;
        float p = __expf(sv) * valid;
        pk[r] = (short)f2bf(p);
        l_run += bf2f((unsigned short)pk[r]);
      }
      *(short4v*)&Pl[wv][l15][mt*16 + quad*4] = pk;
    }
    // PV from LDS
    #pragma unroll
    for(int kk=0;kk<2;kk++){
      short8 ap = *(const short8*)&Pl[wv][l15][kk*32 + quad*8];
      #pragma unroll
      for(int nt=0;nt<8;nt++){
        short8 bv = *(const short8*)&Vl[nt*16+l15][kk*32 + quad*8];
        accPV[nt] = MFMA(ap, bv, accPV[nt]);
      }
    }
  }
  l_run += __shfl_xor(l_run, 16, 64);
  l_run += __shfl_xor(l_run, 32, 64);

  // per-wave projection (Al slice is wave-private; no cross-wave barrier needed)
  #pragma unroll
  for(int nt=0;nt<8;nt++)
    #pragma unroll
    for(int r=0;r<4;r++){
      float av = fminf(fmaxf(accPV[nt][r], -1e30f), 1e30f);
      Al[wv][quad*4+r][nt*16+l15] = (short)f2bf(av);
    }

  const int qc = qbase + l15;
  const bool qok = (qc < na);                // predicate loads of aidx + stores only
  const float linv = (l_run > 0.f) ? 1.f/l_run : 0.f;
  const int node = aidx[(size_t)t*MM + (qok ? qc : 0)];
  #pragma unroll
  for(int mt2=0;mt2<2;mt2++){
    f32x4 d = zz;
    #pragma unroll
    for(int kk=0;kk<4;kk++){
      short8 aw = *(const short8*)(Wct + (size_t)(mt2*16+l15)*DH + kk*32 + quad*8);
      short8 bl = *(const short8*)&Al[wv][l15][kk*32 + quad*8];
      d = MFMA(aw, bl, d);
    }
    f32x4 bcv = *(const f32x4*)(bc + mt2*16 + quad*4);
    f32x4 o4;
    #pragma unroll
    for(int r=0;r<4;r++) o4[r] = d[r]*linv + bcv[r];
    if(qok)
      *(f32x4*)(out + (size_t)node*(TT*DOUT) + (size_t)t*DOUT + mt2*16 + quad*4) = o4;
  }
}

// ================= launch: 5 kernels (was 7) =================

extern "C" void kernel_launch(void* const* d_in, const int* in_sizes, int n_in,
                              void* d_out, int out_size, void* d_ws, size_t ws_size,
                              hipStream_t stream)
{
  float* outp = (float*)d_out;   // reference output dtype is float32
  static const int EXP[19] = {1572864,50331648,24576,8192,128,16384,128,16,16,
                              18432,128,18432,128,18432,128,16384,128,4096,32};
  bool ok = (n_in >= 19) && (out_size == OUTSZ);
  if(ok) for(int i=0;i<19;i++) if(in_sizes[i] != EXP[i]) { ok = false; break; }
  if(!ok){
    k_fill<<<(out_size+255)/256,256,0,stream>>>(outp, out_size, 1000.f);
    return;
  }
  const void* x   = d_in[0];
  const void* A   = d_in[1];
  const void* eg  = d_in[2];
  const void* w1  = d_in[3];
  const void* b1  = d_in[4];
  const void* w2  = d_in[5];
  const void* b2  = d_in[6];
  const void* tw  = d_in[7];
  const void* tb  = d_in[8];
  const void* qw  = d_in[9];
  const void* qb0 = d_in[10];
  const void* kw  = d_in[11];
  const void* kb0 = d_in[12];
  const void* vw  = d_in[13];
  const void* vb0 = d_in[14];
  const void* ow  = d_in[15];
  const void* ob  = d_in[16];
  const void* fw  = d_in[17];
  const void* fb  = d_in[18];

  char* w = (char*)d_ws;
  size_t off = 0;
  auto alloc = [&](size_t sz)->char*{
    char* p = w + off; off = (off + sz + 255) & ~(size_t)255; return p; };
  int*   dtf   = (int*)  alloc(4);
  int*   nactb = (int*)  alloc(TT*4);
  int*   cnt   = (int*)  alloc((size_t)TM*4);
  int*   aidx  = (int*)  alloc((size_t)TM*4);
  int*   inv   = (int*)  alloc((size_t)TM*4);
  int*   edges = (int*)  alloc((size_t)TM*CAP*4);
  float* g     = (float*)alloc((size_t)TM*DH*4);   // reused as Qb+Kb after k_gg1
  float* g2    = (float*)alloc((size_t)TM*DH*4);   // gg1 output (no in-launch race)
  unsigned short* Vtc = (unsigned short*)alloc((size_t)TT*DH*MM*2);
  unsigned short* W2t = (unsigned short*)alloc(DH*DH*2);
  unsigned short* Wqt = (unsigned short*)alloc(DH*DH*2);
  unsigned short* Wkt = (unsigned short*)alloc(DH*DH*2);
  unsigned short* Wvt = (unsigned short*)alloc(DH*DH*2);
  unsigned short* Wct = (unsigned short*)alloc(DOUT*DH*2);
  float* qbf = (float*)alloc(TT*DH*4);
  float* kbf = (float*)alloc(TT*DH*4);
  float* vbf = (float*)alloc(TT*DH*4);
  float* bcf = (float*)alloc(DOUT*4);
  float* b1f = (float*)alloc(DH*4);
  float* b2f = (float*)alloc(DH*4);
  if(off > ws_size){
    k_fill<<<(out_size+255)/256,256,0,stream>>>(outp, out_size, 500.f);
    return;
  }

  unsigned short* Qb = (unsigned short*)g;                       // TM*DH*2 bytes
  unsigned short* Kb = (unsigned short*)((char*)g + (size_t)TM*DH*2);

  // L1: mask compaction (12 blocks) + x dtype detect (1 block)
  k_maskdet<<<TT+1,256,0,stream>>>(eg, (const unsigned short*)x, dtf,
                                   cnt, nactb, aidx, inv);
  // L2: weight prep + coalesced edge build + gemm_x, one launch
  k_pex<<<PWB + TM*64/256 + TM/64,256,0,stream>>>(
      x, A, w1, w2, qw, kw, vw, qb0, kb0, vb0, ow, ob, fw, fb, tw, tb, b1, b2,
      dtf, inv, cnt, edges, nactb, aidx, g,
      W2t, Wqt, Wkt, Wvt, Wct, qbf, kbf, vbf, bcf, b1f, b2f);
  // L3: fused gather1 + gemm_h  (g -> g2)
  k_gg1<<<TM/64,256,0,stream>>>(g, edges, cnt, nactb, b1f, W2t, g2);
  // L4: fused gather2 + QKV  (g2 -> Qb,Kb,Vtc; Qb/Kb alias dead g)
  k_gqkv<<<TM/64,256,0,stream>>>(g2, edges, cnt, nactb, b2f,
                                 Wqt, Wkt, Wvt, qbf, kbf, vbf, Qb, Kb, Vtc);
  // L5: fused attention + projection + inactive-node zeroing
  k_attn<<<dim3(MM/64,TT),256,0,stream>>>(Qb, Kb, Vtc, nactb, aidx, inv,
                                          Wct, bcf, outp);
}

// Round 9
// 504.604 us; speedup vs baseline: 1.1249x; 1.1249x over previous
//
#include <hip/hip_runtime.h>
#include <stdint.h>

#define TT   12
#define BB   2
#define NN   1024
#define MM   2048
#define TM   24576      // TT*MM
#define DIN  64
#define DH   128
#define DOUT 32
#define CAP  64
#define OUTSZ 786432
#define PWB  292        // prepw blocks (74528 items / 256) inside k_pex

typedef __attribute__((ext_vector_type(8))) short short8;
typedef __attribute__((ext_vector_type(4))) short short4v;
typedef __attribute__((ext_vector_type(4))) float f32x4;

#define MFMA(a,b,c) __builtin_amdgcn_mfma_f32_16x16x32_bf16((a),(b),(c),0,0,0)

__device__ __forceinline__ float bf2f(unsigned short u){
  union { uint32_t i; float f; } x; x.i = ((uint32_t)u) << 16; return x.f;
}
__device__ __forceinline__ unsigned short f2bf(float f){
  union { float f; uint32_t i; } x; x.f = f;
  uint32_t u = x.i + 0x7FFFu + ((x.i >> 16) & 1u);   // RNE
  return (unsigned short)(u >> 16);
}
__device__ __forceinline__ float LD(const void* p, size_t i, int mode){
  return mode ? ((const float*)p)[i] : bf2f(((const unsigned short*)p)[i]);
}
// gather-load 8 input elements as bf16 (mode 1 = fp32 source)
__device__ __forceinline__ short8 ldx8(const void* x, size_t off, int md){
  if(md){
    const float4* xf = (const float4*)((const float*)x + off);
    float4 a = xf[0], b = xf[1];
    short8 o;
    o[0]=(short)f2bf(a.x); o[1]=(short)f2bf(a.y); o[2]=(short)f2bf(a.z); o[3]=(short)f2bf(a.w);
    o[4]=(short)f2bf(b.x); o[5]=(short)f2bf(b.y); o[6]=(short)f2bf(b.z); o[7]=(short)f2bf(b.w);
    return o;
  }
  return *(const short8*)((const unsigned short*)x + off);
}

// ---------------- fill (fp32, sentinels only) ----------------
__global__ void k_fill(float* __restrict__ out, int n, float val){
  int i = blockIdx.x*blockDim.x + threadIdx.x;
  if(i < n) out[i] = val;
}

// ---------------- L1: mask decode + x-dtype detect + out zero ----------------
// Blocks 0..TT-1: per-block redundant mask-dtype detect (24KB eg scan, L2) then
// LDS-prefix compaction of timestep t (deterministic, no global atomics).
// Block TT: x dtype detect -> dtf. All 3072 blocks zero out.
__global__ __launch_bounds__(256) void k_maskdet(
    const void* __restrict__ egom, const unsigned short* __restrict__ xs,
    int* __restrict__ dtf,
    int* __restrict__ cnt, int* __restrict__ nact,
    int* __restrict__ aidx, int* __restrict__ inv,
    float* __restrict__ out)
{
  const int bid = blockIdx.x, tid = threadIdx.x;
  out[(size_t)bid*256 + tid] = 0.f;          // inactive nodes stay 0
  if(bid > TT) return;
  if(bid == TT){                             // x dtype detect
    __shared__ int cnt_s;
    if(tid == 0) cnt_s = 0;
    __syncthreads();
    int c = 0;
    for(int i = tid; i < 6144; i += 256){
      unsigned short hh = xs[i*2];
      unsigned e = (hh >> 7) & 0xFF;
      if(hh==0 || (e >= 0x60 && e <= 0x9F)) c++;
    }
    if(c) atomicAdd(&cnt_s, c);
    __syncthreads();
    if(tid == 0) *dtf = (cnt_s > 4000) ? 0 : 1;   // 0=bf16, 1=fp32
    return;
  }
  const int t = bid, lane = tid & 63, wv = tid >> 6;

  __shared__ int pres_s, ge2_s, wcnt_s[4];
  if(tid == 0){ pres_s = 0; ge2_s = 0; }
  __syncthreads();
  {
    int pres = 0, ge2 = 0;
    const unsigned char* egp = (const unsigned char*)egom;
    for(int i = tid; i < 24576; i += 256){
      unsigned v = egp[i];
      if(v){ pres |= 1 << (i & 7); if(v >= 2u) ge2 = 1; }
    }
    if(pres) atomicOr(&pres_s, pres);
    if(ge2)  atomicOr(&ge2_s, 1);
  }
  __syncthreads();
  int mode;
  {
    int pr = pres_s, g2 = ge2_s;
    if(!g2){
      if((pr & ~0x01) == 0)      mode = 4;   // i64
      else if((pr & ~0x11) == 0) mode = 0;   // i32
      else                       mode = 1;   // u8
    } else {
      if((pr & ~0xC0) == 0)      mode = 5;   // f64
      else if((pr & ~0xCC) == 0) mode = 3;   // f32
      else                       mode = 2;   // bf16
    }
  }

  int base = 0;                              // uniform running prefix (register)
  for(int r = 0; r < 8; r++){
    int node = r*256 + tid;
    int b = node / NN, n = node % NN;
    int src = (b*TT + t)*NN + n;
    int v;
    if(mode==0)      v = ((const int*)egom)[src] != 0;
    else if(mode==1) v = ((const unsigned char*)egom)[src] != 0;
    else if(mode==2) v = ((const unsigned short*)egom)[src] != 0;
    else if(mode==3) v = ((const float*)egom)[src] != 0.f;
    else if(mode==4) v = ((const long long*)egom)[src] != 0;
    else             v = ((const double*)egom)[src] != 0.0;
    cnt[(size_t)t*MM + node] = 0;
    unsigned long long bal = __ballot(v != 0);
    if(lane == 0) wcnt_s[wv] = __popcll(bal);
    __syncthreads();
    int mybase = base;
    for(int w2 = 0; w2 < wv; w2++) mybase += wcnt_s[w2];
    int ic = -1;
    if(v){
      ic = mybase + __popcll(bal & ((1ULL << lane) - 1ULL));
      aidx[(size_t)t*MM + ic] = node;
    }
    inv[(size_t)t*MM + node] = ic;
    base += wcnt_s[0] + wcnt_s[1] + wcnt_s[2] + wcnt_s[3];
    __syncthreads();                        // protect wcnt_s before next round
  }
  if(tid == 0) nact[t] = base;
}

// ================= device bodies =================

// weight prep WITHOUT the W1t segment (gemm_x reads w1 directly). 74528 items.
__device__ __forceinline__ void dev_prepw2_item(int id, int md,
  const void* w2,
  const void* qw, const void* kw, const void* vw,
  const void* qb0, const void* kb0, const void* vb0,
  const void* ow, const void* ob, const void* fw, const void* fb,
  const void* tw, const void* tb, const void* b1, const void* b2,
  unsigned short* W2t,
  unsigned short* Wqt, unsigned short* Wkt,
  unsigned short* Wvt, unsigned short* Wct,
  float* qbf, float* kbf, float* vbf,
  float* bcf, float* b1f, float* b2f)
{
  if(id < 16384){ int n=id&127,k2=id>>7; W2t[n*128+k2]=f2bf(LD(w2,(size_t)k2*128+n,md)); return; }
  id -= 16384;
  if(id < 16384){ int n=id&127,k2=id>>7; Wqt[n*128+k2]=f2bf(LD(qw,(size_t)k2*128+n,md)); return; }
  id -= 16384;
  if(id < 16384){ int n=id&127,k2=id>>7; Wkt[n*128+k2]=f2bf(LD(kw,(size_t)k2*128+n,md)); return; }
  id -= 16384;
  if(id < 16384){ int n=id&127,k2=id>>7; Wvt[n*128+k2]=f2bf(LD(vw,(size_t)k2*128+n,md)); return; }
  id -= 16384;
  if(id < 4096){  // Wc = o_w @ fc_w, stored [oc][c]
    int oc=id&31, c=id>>5; float s=0.f;
    for(int r=0;r<128;r++) s += LD(ow,(size_t)c*128+r,md)*LD(fw,(size_t)r*32+oc,md);
    Wct[oc*128+c]=f2bf(s); return;
  }
  id -= 4096;
  if(id < 32){    // bc = o_b @ fc_w + fc_b
    float s = LD(fb,id,md);
    for(int r=0;r<128;r++) s += LD(ob,r,md)*LD(fw,(size_t)r*32+id,md);
    bcf[id]=s; return;
  }
  id -= 32;
  if(id < 4608){  // per-t fused QKV bias: b + t_vec @ W[128:144]
    int which = id/1536, rem=id%1536, t=rem/128, n=rem%128;
    const void* W  = which==0?qw:(which==1?kw:vw);
    const void* Bs = which==0?qb0:(which==1?kb0:vb0);
    float s = LD(Bs,n,md);
    for(int d=0;d<16;d++){
      float tv = sinf((float)t*LD(tw,d,md) + LD(tb,d,md));
      s += tv * LD(W,(size_t)(128+d)*128+n,md);
    }
    float* dst = which==0?qbf:(which==1?kbf:vbf);
    dst[t*128+n]=s; return;
  }
  id -= 4608;
  if(id < 256){   // GCN biases to fp32
    if(id<128) b1f[id] = LD(b1,id,md);
    else       b2f[id-128] = LD(b2,id-128,md);
    return;
  }
}

// COALESCED edge scan: one wave per row, lane i + iter u reads vector index
// u*64+i -> consecutive lanes touch consecutive 16B (1KB/wave-instruction).
__device__ __forceinline__ void dev_edges_item(int id, int md,
    const void* A, const int* inv, int* cnt, int* edges){
  int lane = id & 63; int row = id >> 6;          // row = t*MM + j (orig)
  int t = row / MM;
  int jc = inv[row];
  if(jc < 0) return;                              // inactive source
  const int* invt = inv + (size_t)t*MM;
  int* cb = cnt + (size_t)t*MM;
  int* eb = edges + (size_t)t*MM*CAP;
  if(md){   // fp32 adjacency: 512 float4 per row
    const float4* p4 = (const float4*)((const float*)A + (size_t)row*MM);
    #pragma unroll
    for(int u=0;u<8;u++){
      float4 v = p4[u*64 + lane];
      float wd[4]={v.x,v.y,v.z,v.w};
      #pragma unroll
      for(int q=0;q<4;q++){
        if(wd[q]!=0.f){
          int ibc = invt[(u*64 + lane)*4 + q];
          if(ibc >= 0){ int s=atomicAdd(&cb[ibc],1); if(s<CAP) eb[(size_t)ibc*CAP+s]=jc; }
        }
      }
    }
  } else {    // bf16 adjacency: 256 uint4 per row (8 bf16 each)
    const uint4* p4 = (const uint4*)((const unsigned short*)A + (size_t)row*MM);
    #pragma unroll
    for(int u=0;u<4;u++){
      uint4 v = p4[u*64 + lane];
      unsigned wd[4]={v.x,v.y,v.z,v.w};
      #pragma unroll
      for(int q=0;q<4;q++){
        int ib = (u*64 + lane)*8 + q*2;
        if(wd[q] & 0xFFFFu){
          int ibc = invt[ib];
          if(ibc >= 0){ int s=atomicAdd(&cb[ibc],1); if(s<CAP) eb[(size_t)ibc*CAP+s]=jc; }
        }
        if(wd[q] >> 16){
          int ibc = invt[ib+1];
          if(ibc >= 0){ int s=atomicAdd(&cb[ibc],1); if(s<CAP) eb[(size_t)ibc*CAP+s]=jc; }
        }
      }
    }
  }
}

// gemm_x reading w1 DIRECTLY (transposed access; w1 is 32KB, L2-hot)
__device__ __forceinline__ void dev_gemm_x_direct(int tileIdx, int md, int tid,
    const void* x, const int* nact, const int* aidx,
    const void* w1, float* g)
{
  const int tile = tileIdx*64;
  const int t = tile / MM, il = tile % MM;
  const int na = nact[t];
  if(il >= ((na+63)&~63)) return;
  const int wv=tid>>6, lane=tid&63, l15=lane&15, quad=lane>>4;
  const int r0 = tile + (wv>>1)*32;          // global compact row base
  const int c0 = (wv&1)*64;
  short8 bf[2][4];
  #pragma unroll
  for(int kk=0;kk<2;kk++)
    #pragma unroll
    for(int nt=0;nt<4;nt++){
      const int col = c0+nt*16+l15;
      short8 o;
      #pragma unroll
      for(int j=0;j<8;j++)
        o[j] = (short)f2bf(LD(w1, (size_t)(kk*32 + quad*8 + j)*DH + col, md));
      bf[kk][nt] = o;
    }
  const int il0 = (r0 % MM) + l15, il1 = (r0 % MM) + 16 + l15;
  const int n0 = aidx[(size_t)t*MM + (il0 < na ? il0 : 0)];
  const int n1 = aidx[(size_t)t*MM + (il1 < na ? il1 : 0)];
  const size_t xb0 = ((size_t)t*MM + n0)*DIN;
  const size_t xb1 = ((size_t)t*MM + n1)*DIN;
  f32x4 z = {0.f,0.f,0.f,0.f};
  f32x4 acc[2][4];
  #pragma unroll
  for(int i=0;i<2;i++){ acc[i][0]=z; acc[i][1]=z; acc[i][2]=z; acc[i][3]=z; }
  #pragma unroll
  for(int kk=0;kk<2;kk++){
    short8 a0 = ldx8(x, xb0 + kk*32 + quad*8, md);
    short8 a1 = ldx8(x, xb1 + kk*32 + quad*8, md);
    #pragma unroll
    for(int nt=0;nt<4;nt++){
      acc[0][nt]=MFMA(a0,bf[kk][nt],acc[0][nt]);
      acc[1][nt]=MFMA(a1,bf[kk][nt],acc[1][nt]);
    }
  }
  #pragma unroll
  for(int mt=0;mt<2;mt++)
    #pragma unroll
    for(int nt=0;nt<4;nt++){
      int col = c0+nt*16+l15;
      #pragma unroll
      for(int r=0;r<4;r++){
        int row = r0 + mt*16 + quad*4 + r;
        g[(size_t)row*DH + col] = acc[mt][nt][r];
      }
    }
}

// ---------------- L2: prepw + edges + gemm_x in one launch ----------------
__global__ __launch_bounds__(256) void k_pex(
  const void* __restrict__ x, const void* __restrict__ A,
  const void* __restrict__ w1, const void* __restrict__ w2,
  const void* __restrict__ qw, const void* __restrict__ kw, const void* __restrict__ vw,
  const void* __restrict__ qb0, const void* __restrict__ kb0, const void* __restrict__ vb0,
  const void* __restrict__ ow, const void* __restrict__ ob,
  const void* __restrict__ fw, const void* __restrict__ fb,
  const void* __restrict__ tw, const void* __restrict__ tb,
  const void* __restrict__ b1, const void* __restrict__ b2,
  const int* __restrict__ dtf,
  const int* __restrict__ inv, int* __restrict__ cnt, int* __restrict__ edges,
  const int* __restrict__ nact, const int* __restrict__ aidx, float* __restrict__ g,
  unsigned short* __restrict__ W2t,
  unsigned short* __restrict__ Wqt, unsigned short* __restrict__ Wkt,
  unsigned short* __restrict__ Wvt, unsigned short* __restrict__ Wct,
  float* __restrict__ qbf, float* __restrict__ kbf, float* __restrict__ vbf,
  float* __restrict__ bcf, float* __restrict__ b1f, float* __restrict__ b2f)
{
  const int tid = threadIdx.x;
  const int md = *dtf;                       // produced by k_maskdet block TT
  const int b = blockIdx.x;
  if(b < PWB){
    dev_prepw2_item(b*256 + tid, md, w2, qw,kw,vw, qb0,kb0,vb0, ow,ob,fw,fb, tw,tb, b1,b2,
                    W2t, Wqt, Wkt, Wvt, Wct, qbf, kbf, vbf, bcf, b1f, b2f);
  } else if(b < PWB + TM*64/256){
    dev_edges_item((b - PWB)*256 + tid, md, A, inv, cnt, edges);
  } else {
    dev_gemm_x_direct(b - PWB - TM*64/256, md, tid, x, nact, aidx, w1, g);
  }
}

// ---------------- dense GEMM on compact rows (h -> g), KD=128 ----------------
__global__ __launch_bounds__(256) void k_gemm_h(const unsigned short* __restrict__ X,
    const unsigned short* __restrict__ Wt, float* __restrict__ g,
    const int* __restrict__ nact)
{
  const int tile = blockIdx.x*64;
  const int t = tile / MM, il = tile % MM;
  const int na = nact[t];
  if(il >= ((na+63)&~63)) return;
  const int tid=threadIdx.x, wv=tid>>6, lane=tid&63, l15=lane&15, quad=lane>>4;
  const int r0 = tile + (wv>>1)*32;
  const int c0 = (wv&1)*64;
  short8 bf[4][4];
  #pragma unroll
  for(int kk=0;kk<4;kk++)
    #pragma unroll
    for(int nt=0;nt<4;nt++)
      bf[kk][nt] = *(const short8*)(Wt + (size_t)(c0+nt*16+l15)*DH + kk*32 + quad*8);
  f32x4 z = {0.f,0.f,0.f,0.f};
  f32x4 acc[2][4];
  #pragma unroll
  for(int i=0;i<2;i++){ acc[i][0]=z; acc[i][1]=z; acc[i][2]=z; acc[i][3]=z; }
  #pragma unroll
  for(int kk=0;kk<4;kk++){
    short8 a0 = *(const short8*)(X + (size_t)(r0+l15)*DH    + kk*32 + quad*8);
    short8 a1 = *(const short8*)(X + (size_t)(r0+16+l15)*DH + kk*32 + quad*8);
    #pragma unroll
    for(int nt=0;nt<4;nt++){
      acc[0][nt]=MFMA(a0,bf[kk][nt],acc[0][nt]);
      acc[1][nt]=MFMA(a1,bf[kk][nt],acc[1][nt]);
    }
  }
  #pragma unroll
  for(int mt=0;mt<2;mt++)
    #pragma unroll
    for(int nt=0;nt<4;nt++){
      int col = c0+nt*16+l15;
      #pragma unroll
      for(int r=0;r<4;r++){
        int row = r0 + mt*16 + quad*4 + r;
        g[(size_t)row*DH + col] = acc[mt][nt][r];
      }
    }
}

// ---------------- sparse GCN aggregation on compact rows -> h (bf16) ----------------
__global__ __launch_bounds__(256) void k_gather(const float* __restrict__ g,
    const int* __restrict__ edges, const int* __restrict__ cnt,
    const int* __restrict__ nact, const float* __restrict__ bias,
    unsigned short* __restrict__ h)
{
  int wv = threadIdx.x>>6, lane = threadIdx.x&63;
  int gi = blockIdx.x*4 + wv;           // compact row, < TM
  int t = gi / MM, ic = gi % MM;
  int na = nact[t];
  if(ic >= ((na+63)&~63)) return;
  unsigned int* hp = (unsigned int*)(h + (size_t)gi*DH) + lane;
  if(ic >= na){ *hp = 0; return; }      // pad row: finite zeros
  float a0=0.f, a1=0.f;
  int cn = cnt[gi]; if(cn>CAP) cn=CAP;
  const int* eb = edges + (size_t)gi*CAP;
  #pragma unroll 2
  for(int e=0;e<cn;e++){
    int jc = eb[e];
    float nj = rsqrtf((float)cnt[(size_t)t*MM+jc] + 1.f);
    float2 gr2 = *(const float2*)(g + ((size_t)t*MM + jc)*DH + 2*lane);
    a0 += nj*gr2.x; a1 += nj*gr2.y;
  }
  float ni = rsqrtf((float)cn + 1.f);
  float2 gs2 = *(const float2*)(g + (size_t)gi*DH + 2*lane);
  float h0 = ni*(a0 + ni*gs2.x) + bias[2*lane];
  float h1 = ni*(a1 + ni*gs2.y) + bias[2*lane+1];
  h0 = h0>0.f?h0:0.f; h1 = h1>0.f?h1:0.f;
  *hp = (unsigned int)f2bf(h0) | ((unsigned int)f2bf(h1) << 16);
}

// ---------------- Q/K/V GEMMs: Q,K row-major; V written TRANSPOSED directly ----------------
__global__ __launch_bounds__(256) void k_gemm_qkv(const unsigned short* __restrict__ X,
    const unsigned short* __restrict__ Wq, const unsigned short* __restrict__ Wk,
    const unsigned short* __restrict__ Wv,
    const float* __restrict__ qb, const float* __restrict__ kb, const float* __restrict__ vb,
    unsigned short* __restrict__ Qo, unsigned short* __restrict__ Ko,
    unsigned short* __restrict__ Vtc, const int* __restrict__ nact)
{
  const int tile = blockIdx.x*64;
  const int t = tile / MM, il = tile % MM;
  const int na = nact[t];
  if(il >= ((na+63)&~63)) return;
  const int which = blockIdx.z;
  const unsigned short* Wt = which==0?Wq:(which==1?Wk:Wv);
  const float* bias = which==0?qb:(which==1?kb:vb);
  const int tid=threadIdx.x, wv=tid>>6, lane=tid&63, l15=lane&15, quad=lane>>4;
  const int r0 = tile + (wv>>1)*32;
  const int c0 = (wv&1)*64;
  short8 bf[4][4];
  #pragma unroll
  for(int kk=0;kk<4;kk++)
    #pragma unroll
    for(int nt=0;nt<4;nt++)
      bf[kk][nt] = *(const short8*)(Wt + (size_t)(c0+nt*16+l15)*DH + kk*32 + quad*8);
  f32x4 z = {0.f,0.f,0.f,0.f};
  f32x4 acc[2][4];
  #pragma unroll
  for(int i=0;i<2;i++){ acc[i][0]=z; acc[i][1]=z; acc[i][2]=z; acc[i][3]=z; }
  #pragma unroll
  for(int kk=0;kk<4;kk++){
    short8 a0 = *(const short8*)(X + (size_t)(r0+l15)*DH    + kk*32 + quad*8);
    short8 a1 = *(const short8*)(X + (size_t)(r0+16+l15)*DH + kk*32 + quad*8);
    #pragma unroll
    for(int nt=0;nt<4;nt++){
      acc[0][nt]=MFMA(a0,bf[kk][nt],acc[0][nt]);
      acc[1][nt]=MFMA(a1,bf[kk][nt],acc[1][nt]);
    }
  }
  if(which < 2){
    unsigned short* o = which==0 ? Qo : Ko;
    #pragma unroll
    for(int mt=0;mt<2;mt++)
      #pragma unroll
      for(int nt=0;nt<4;nt++){
        int col = c0+nt*16+l15;
        float bb = bias[t*DH+col];
        #pragma unroll
        for(int r=0;r<4;r++){
          int row = r0 + mt*16 + quad*4 + r;
          o[(size_t)row*DH + col] = f2bf(acc[mt][nt][r] + bb);
        }
      }
  } else {
    #pragma unroll
    for(int mt=0;mt<2;mt++)
      #pragma unroll
      for(int nt=0;nt<4;nt++){
        int col = c0+nt*16+l15;
        float bb = bias[t*DH+col];
        int node0 = il + (wv>>1)*32 + mt*16 + quad*4;   // compact local row
        short4v pk;
        #pragma unroll
        for(int r=0;r<4;r++) pk[r] = (short)f2bf(acc[mt][nt][r] + bb);
        *(short4v*)(Vtc + ((size_t)t*DH + col)*MM + node0) = pk;
      }
  }
}

// ---------------- fused attention: double-buffered LDS (1 barrier/tile) ----------------
// 98.3KB LDS -> 1 block/CU; with only ~192 active blocks on 256 CUs this was
// already the effective occupancy. Halves the barrier count of the K-loop.
__global__ __launch_bounds__(256) void k_attn(
  const unsigned short* __restrict__ Q, const unsigned short* __restrict__ Kc,
  const unsigned short* __restrict__ Vtc, const int* __restrict__ nact,
  const int* __restrict__ aidx, const unsigned short* __restrict__ Wct,
  const float* __restrict__ bc, float* __restrict__ out)
{
  __shared__ unsigned short Kl[2][64][136];   // 2 x (64 keys x 128ch)
  __shared__ unsigned short Vl[2][128][72];   // 2 x (128 ch x 64 keys)
  __shared__ short Pl[4][16][72];             // per-wave P tile
  __shared__ short Al[4][16][136];            // per-wave accumulator for projection
  const int tid=threadIdx.x, wv=tid>>6, lane=tid&63, l15=lane&15, quad=lane>>4;
  const int t = blockIdx.y;
  const int na = nact[t];
  const int qblk = blockIdx.x*64;
  if(qblk >= na) return;                 // block-uniform exit (before any barrier)
  const int qbase = qblk + wv*16;
  const float scale = 0.088388347648318447f;  // 1/sqrt(128)
  const int nkt = (na + 63) >> 6;

  short8 bq[4];
  #pragma unroll
  for(int kk=0;kk<4;kk++)
    bq[kk] = *(const short8*)(Q + ((size_t)t*MM + qbase + l15)*DH + kk*32 + quad*8);

  f32x4 zz = {0.f,0.f,0.f,0.f};
  f32x4 accPV[8];
  #pragma unroll
  for(int i=0;i<8;i++) accPV[i]=zz;
  float l_run = 0.f;

  const int srow = tid >> 2, sseg = tid & 3;   // K stage: 64 rows x 4 segs
  const int vch  = tid >> 1, vhalf = tid & 1;  // V stage: 128 ch x 2 halves

  short8 kreg[4], vreg[4];
  {  // preload tile 0 into registers, stage to buffer 0
    const unsigned short* gk = Kc + ((size_t)t*MM + srow)*DH + sseg*32;
    const unsigned short* gv = Vtc + ((size_t)t*DH + vch)*MM + vhalf*32;
    #pragma unroll
    for(int j=0;j<4;j++){ kreg[j] = *(const short8*)(gk + j*8);
                          vreg[j] = *(const short8*)(gv + j*8); }
    short8* kd = (short8*)&Kl[0][srow][sseg*32];
    short8* vd = (short8*)&Vl[0][vch][vhalf*32];
    #pragma unroll
    for(int j=0;j<4;j++){ kd[j] = kreg[j]; vd[j] = vreg[j]; }
  }
  __syncthreads();

  int cur = 0;
  for(int kt=0; kt<nkt; kt++){
    const int key0 = kt*64;
    if(kt+1 < nkt){   // issue next tile's global loads; they overlap compute below
      const int key1 = key0 + 64;
      const unsigned short* gk = Kc + ((size_t)t*MM + key1 + srow)*DH + sseg*32;
      const unsigned short* gv = Vtc + ((size_t)t*DH + vch)*MM + key1 + vhalf*32;
      #pragma unroll
      for(int j=0;j<4;j++){ kreg[j] = *(const short8*)(gk + j*8);
                            vreg[j] = *(const short8*)(gv + j*8); }
    }
    // S^T = K · Q^T from LDS buffer cur
    #pragma unroll
    for(int mt=0;mt<4;mt++){
      f32x4 s = zz;
      #pragma unroll
      for(int kk=0;kk<4;kk++){
        short8 ak = *(const short8*)&Kl[cur][mt*16+l15][kk*32 + quad*8];
        s = MFMA(ak, bq[kk], s);
      }
      short4v pk;
      #pragma unroll
      for(int r=0;r<4;r++){
        float sv = fminf(fmaxf(s[r]*scale, -15.f), 15.f);
        float valid = (key0 + mt*16 + quad*4 + r < na) ? 1.f : 0.f;
        float p = __expf(sv) * valid;
        pk[r] = (short)f2bf(p);
        l_run += bf2f((unsigned short)pk[r]);
      }
      *(short4v*)&Pl[wv][l15][mt*16 + quad*4] = pk;
    }
    // PV from LDS buffer cur
    #pragma unroll
    for(int kk=0;kk<2;kk++){
      short8 ap = *(const short8*)&Pl[wv][l15][kk*32 + quad*8];
      #pragma unroll
      for(int nt=0;nt<8;nt++){
        short8 bv = *(const short8*)&Vl[cur][nt*16+l15][kk*32 + quad*8];
        accPV[nt] = MFMA(ap, bv, accPV[nt]);
      }
    }
    if(kt+1 < nkt){   // stage next tile to the other buffer; 1 barrier/iteration
      short8* kd = (short8*)&Kl[cur^1][srow][sseg*32];
      short8* vd = (short8*)&Vl[cur^1][vch][vhalf*32];
      #pragma unroll
      for(int j=0;j<4;j++){ kd[j] = kreg[j]; vd[j] = vreg[j]; }
      __syncthreads();
      cur ^= 1;
    }
  }
  l_run += __shfl_xor(l_run, 16, 64);
  l_run += __shfl_xor(l_run, 32, 64);

  // per-wave projection (Al slice is wave-private; no cross-wave barrier needed)
  #pragma unroll
  for(int nt=0;nt<8;nt++)
    #pragma unroll
    for(int r=0;r<4;r++){
      float av = fminf(fmaxf(accPV[nt][r], -1e30f), 1e30f);
      Al[wv][quad*4+r][nt*16+l15] = (short)f2bf(av);
    }

  const int qc = qbase + l15;
  const bool qok = (qc < na);                // predicate loads of aidx + stores only
  const float linv = (l_run > 0.f) ? 1.f/l_run : 0.f;
  const int node = aidx[(size_t)t*MM + (qok ? qc : 0)];
  #pragma unroll
  for(int mt2=0;mt2<2;mt2++){
    f32x4 d = zz;
    #pragma unroll
    for(int kk=0;kk<4;kk++){
      short8 aw = *(const short8*)(Wct + (size_t)(mt2*16+l15)*DH + kk*32 + quad*8);
      short8 bl = *(const short8*)&Al[wv][l15][kk*32 + quad*8];
      d = MFMA(aw, bl, d);
    }
    f32x4 bcv = *(const f32x4*)(bc + mt2*16 + quad*4);
    f32x4 o4;
    #pragma unroll
    for(int r=0;r<4;r++) o4[r] = d[r]*linv + bcv[r];
    if(qok)
      *(f32x4*)(out + (size_t)node*(TT*DOUT) + (size_t)t*DOUT + mt2*16 + quad*4) = o4;
  }
}

// ================= launch: 7 kernels =================

extern "C" void kernel_launch(void* const* d_in, const int* in_sizes, int n_in,
                              void* d_out, int out_size, void* d_ws, size_t ws_size,
                              hipStream_t stream)
{
  float* outp = (float*)d_out;   // reference output dtype is float32
  static const int EXP[19] = {1572864,50331648,24576,8192,128,16384,128,16,16,
                              18432,128,18432,128,18432,128,16384,128,4096,32};
  bool ok = (n_in >= 19) && (out_size == OUTSZ);
  if(ok) for(int i=0;i<19;i++) if(in_sizes[i] != EXP[i]) { ok = false; break; }
  if(!ok){
    k_fill<<<(out_size+255)/256,256,0,stream>>>(outp, out_size, 1000.f);
    return;
  }
  const void* x   = d_in[0];
  const void* A   = d_in[1];
  const void* eg  = d_in[2];
  const void* w1  = d_in[3];
  const void* b1  = d_in[4];
  const void* w2  = d_in[5];
  const void* b2  = d_in[6];
  const void* tw  = d_in[7];
  const void* tb  = d_in[8];
  const void* qw  = d_in[9];
  const void* qb0 = d_in[10];
  const void* kw  = d_in[11];
  const void* kb0 = d_in[12];
  const void* vw  = d_in[13];
  const void* vb0 = d_in[14];
  const void* ow  = d_in[15];
  const void* ob  = d_in[16];
  const void* fw  = d_in[17];
  const void* fb  = d_in[18];

  char* w = (char*)d_ws;
  size_t off = 0;
  auto alloc = [&](size_t sz)->char*{
    char* p = w + off; off = (off + sz + 255) & ~(size_t)255; return p; };
  int*   dtf   = (int*)  alloc(4);
  int*   nactb = (int*)  alloc(TT*4);
  int*   cnt   = (int*)  alloc((size_t)TM*4);
  int*   aidx  = (int*)  alloc((size_t)TM*4);
  int*   inv   = (int*)  alloc((size_t)TM*4);
  int*   edges = (int*)  alloc((size_t)TM*CAP*4);
  float* g     = (float*)alloc((size_t)TM*DH*4);   // reused as Qb+Kb after 2nd gather
  unsigned short* h   = (unsigned short*)alloc((size_t)TM*DH*2);
  unsigned short* Vtc = (unsigned short*)alloc((size_t)TT*DH*MM*2);
  unsigned short* W2t = (unsigned short*)alloc(DH*DH*2);
  unsigned short* Wqt = (unsigned short*)alloc(DH*DH*2);
  unsigned short* Wkt = (unsigned short*)alloc(DH*DH*2);
  unsigned short* Wvt = (unsigned short*)alloc(DH*DH*2);
  unsigned short* Wct = (unsigned short*)alloc(DOUT*DH*2);
  float* qbf = (float*)alloc(TT*DH*4);
  float* kbf = (float*)alloc(TT*DH*4);
  float* vbf = (float*)alloc(TT*DH*4);
  float* bcf = (float*)alloc(DOUT*4);
  float* b1f = (float*)alloc(DH*4);
  float* b2f = (float*)alloc(DH*4);
  if(off > ws_size){
    k_fill<<<(out_size+255)/256,256,0,stream>>>(outp, out_size, 500.f);
    return;
  }

  unsigned short* Qb = (unsigned short*)g;                       // TM*DH*2 bytes
  unsigned short* Kb = (unsigned short*)((char*)g + (size_t)TM*DH*2);

  // L1: mask (deterministic per-t compaction) + x dtype detect + out zero
  k_maskdet<<<OUTSZ/256,256,0,stream>>>(eg, (const unsigned short*)x, dtf,
                                        cnt, nactb, aidx, inv, outp);
  // L2: weight prep + COALESCED edge build + gemm_x (direct w1 reads), one launch
  k_pex<<<PWB + TM*64/256 + TM/64,256,0,stream>>>(
      x, A, w1, w2, qw, kw, vw, qb0, kb0, vb0, ow, ob, fw, fb, tw, tb, b1, b2,
      dtf, inv, cnt, edges, nactb, aidx, g,
      W2t, Wqt, Wkt, Wvt, Wct, qbf, kbf, vbf, bcf, b1f, b2f);
  // L3..L6: GCN + QKV
  k_gather<<<TM/4,256,0,stream>>>(g, edges, cnt, nactb, b1f, h);
  k_gemm_h<<<TM/64,256,0,stream>>>(h, W2t, g, nactb);
  k_gather<<<TM/4,256,0,stream>>>(g, edges, cnt, nactb, b2f, h);
  k_gemm_qkv<<<dim3(TM/64,1,3),256,0,stream>>>(h, Wqt,Wkt,Wvt, qbf,kbf,vbf, Qb,Kb,Vtc, nactb);
  // L7: double-buffered fused attention + projection
  k_attn<<<dim3(MM/64,TT),256,0,stream>>>(Qb, Kb, Vtc, nactb, aidx, Wct, bcf, outp);
}

// Round 10
// 473.805 us; speedup vs baseline: 1.1980x; 1.0650x over previous
//
#include <hip/hip_runtime.h>
#include <stdint.h>

#define TT   12
#define BB   2
#define NN   1024
#define MM   2048
#define TM   24576      // TT*MM
#define DIN  64
#define DH   128
#define DOUT 32
#define CAP  64
#define OUTSZ 786432
#define PWB  292        // prepw blocks (74528 items / 256) inside k_pex

typedef __attribute__((ext_vector_type(8))) short short8;
typedef __attribute__((ext_vector_type(4))) short short4v;
typedef __attribute__((ext_vector_type(4))) float f32x4;

#define MFMA(a,b,c) __builtin_amdgcn_mfma_f32_16x16x32_bf16((a),(b),(c),0,0,0)

__device__ __forceinline__ float bf2f(unsigned short u){
  union { uint32_t i; float f; } x; x.i = ((uint32_t)u) << 16; return x.f;
}
__device__ __forceinline__ unsigned short f2bf(float f){
  union { float f; uint32_t i; } x; x.f = f;
  uint32_t u = x.i + 0x7FFFu + ((x.i >> 16) & 1u);   // RNE
  return (unsigned short)(u >> 16);
}
__device__ __forceinline__ float LD(const void* p, size_t i, int mode){
  return mode ? ((const float*)p)[i] : bf2f(((const unsigned short*)p)[i]);
}
// gather-load 8 input elements as bf16 (mode 1 = fp32 source)
__device__ __forceinline__ short8 ldx8(const void* x, size_t off, int md){
  if(md){
    const float4* xf = (const float4*)((const float*)x + off);
    float4 a = xf[0], b = xf[1];
    short8 o;
    o[0]=(short)f2bf(a.x); o[1]=(short)f2bf(a.y); o[2]=(short)f2bf(a.z); o[3]=(short)f2bf(a.w);
    o[4]=(short)f2bf(b.x); o[5]=(short)f2bf(b.y); o[6]=(short)f2bf(b.z); o[7]=(short)f2bf(b.w);
    return o;
  }
  return *(const short8*)((const unsigned short*)x + off);
}

// ---------------- fill (fp32, sentinels only) ----------------
__global__ void k_fill(float* __restrict__ out, int n, float val){
  int i = blockIdx.x*blockDim.x + threadIdx.x;
  if(i < n) out[i] = val;
}

// ---------------- L1: mask decode + x-dtype detect + out zero ----------------
// Blocks 0..TT-1: per-block redundant mask-dtype detect (24KB eg scan, L2) then
// LDS-prefix compaction of timestep t (deterministic, no global atomics).
// Block TT: x dtype detect -> dtf. All 3072 blocks zero out.
__global__ __launch_bounds__(256) void k_maskdet(
    const void* __restrict__ egom, const unsigned short* __restrict__ xs,
    int* __restrict__ dtf,
    int* __restrict__ cnt, int* __restrict__ nact,
    int* __restrict__ aidx, int* __restrict__ inv,
    float* __restrict__ out)
{
  const int bid = blockIdx.x, tid = threadIdx.x;
  out[(size_t)bid*256 + tid] = 0.f;          // inactive nodes stay 0
  if(bid > TT) return;
  if(bid == TT){                             // x dtype detect
    __shared__ int cnt_s;
    if(tid == 0) cnt_s = 0;
    __syncthreads();
    int c = 0;
    for(int i = tid; i < 6144; i += 256){
      unsigned short hh = xs[i*2];
      unsigned e = (hh >> 7) & 0xFF;
      if(hh==0 || (e >= 0x60 && e <= 0x9F)) c++;
    }
    if(c) atomicAdd(&cnt_s, c);
    __syncthreads();
    if(tid == 0) *dtf = (cnt_s > 4000) ? 0 : 1;   // 0=bf16, 1=fp32
    return;
  }
  const int t = bid, lane = tid & 63, wv = tid >> 6;

  __shared__ int pres_s, ge2_s, wcnt_s[4];
  if(tid == 0){ pres_s = 0; ge2_s = 0; }
  __syncthreads();
  {
    int pres = 0, ge2 = 0;
    const unsigned char* egp = (const unsigned char*)egom;
    for(int i = tid; i < 24576; i += 256){
      unsigned v = egp[i];
      if(v){ pres |= 1 << (i & 7); if(v >= 2u) ge2 = 1; }
    }
    if(pres) atomicOr(&pres_s, pres);
    if(ge2)  atomicOr(&ge2_s, 1);
  }
  __syncthreads();
  int mode;
  {
    int pr = pres_s, g2 = ge2_s;
    if(!g2){
      if((pr & ~0x01) == 0)      mode = 4;   // i64
      else if((pr & ~0x11) == 0) mode = 0;   // i32
      else                       mode = 1;   // u8
    } else {
      if((pr & ~0xC0) == 0)      mode = 5;   // f64
      else if((pr & ~0xCC) == 0) mode = 3;   // f32
      else                       mode = 2;   // bf16
    }
  }

  int base = 0;                              // uniform running prefix (register)
  for(int r = 0; r < 8; r++){
    int node = r*256 + tid;
    int b = node / NN, n = node % NN;
    int src = (b*TT + t)*NN + n;
    int v;
    if(mode==0)      v = ((const int*)egom)[src] != 0;
    else if(mode==1) v = ((const unsigned char*)egom)[src] != 0;
    else if(mode==2) v = ((const unsigned short*)egom)[src] != 0;
    else if(mode==3) v = ((const float*)egom)[src] != 0.f;
    else if(mode==4) v = ((const long long*)egom)[src] != 0;
    else             v = ((const double*)egom)[src] != 0.0;
    cnt[(size_t)t*MM + node] = 0;
    unsigned long long bal = __ballot(v != 0);
    if(lane == 0) wcnt_s[wv] = __popcll(bal);
    __syncthreads();
    int mybase = base;
    for(int w2 = 0; w2 < wv; w2++) mybase += wcnt_s[w2];
    int ic = -1;
    if(v){
      ic = mybase + __popcll(bal & ((1ULL << lane) - 1ULL));
      aidx[(size_t)t*MM + ic] = node;
    }
    inv[(size_t)t*MM + node] = ic;
    base += wcnt_s[0] + wcnt_s[1] + wcnt_s[2] + wcnt_s[3];
    __syncthreads();                        // protect wcnt_s before next round
  }
  if(tid == 0) nact[t] = base;
}

// ================= device bodies =================

// weight prep WITHOUT the W1t segment (gemm_x reads w1 directly). 74528 items.
__device__ __forceinline__ void dev_prepw2_item(int id, int md,
  const void* w2,
  const void* qw, const void* kw, const void* vw,
  const void* qb0, const void* kb0, const void* vb0,
  const void* ow, const void* ob, const void* fw, const void* fb,
  const void* tw, const void* tb, const void* b1, const void* b2,
  unsigned short* W2t,
  unsigned short* Wqt, unsigned short* Wkt,
  unsigned short* Wvt, unsigned short* Wct,
  float* qbf, float* kbf, float* vbf,
  float* bcf, float* b1f, float* b2f)
{
  if(id < 16384){ int n=id&127,k2=id>>7; W2t[n*128+k2]=f2bf(LD(w2,(size_t)k2*128+n,md)); return; }
  id -= 16384;
  if(id < 16384){ int n=id&127,k2=id>>7; Wqt[n*128+k2]=f2bf(LD(qw,(size_t)k2*128+n,md)); return; }
  id -= 16384;
  if(id < 16384){ int n=id&127,k2=id>>7; Wkt[n*128+k2]=f2bf(LD(kw,(size_t)k2*128+n,md)); return; }
  id -= 16384;
  if(id < 16384){ int n=id&127,k2=id>>7; Wvt[n*128+k2]=f2bf(LD(vw,(size_t)k2*128+n,md)); return; }
  id -= 16384;
  if(id < 4096){  // Wc = o_w @ fc_w, stored [oc][c]
    int oc=id&31, c=id>>5; float s=0.f;
    for(int r=0;r<128;r++) s += LD(ow,(size_t)c*128+r,md)*LD(fw,(size_t)r*32+oc,md);
    Wct[oc*128+c]=f2bf(s); return;
  }
  id -= 4096;
  if(id < 32){    // bc = o_b @ fc_w + fc_b
    float s = LD(fb,id,md);
    for(int r=0;r<128;r++) s += LD(ob,r,md)*LD(fw,(size_t)r*32+id,md);
    bcf[id]=s; return;
  }
  id -= 32;
  if(id < 4608){  // per-t fused QKV bias: b + t_vec @ W[128:144]
    int which = id/1536, rem=id%1536, t=rem/128, n=rem%128;
    const void* W  = which==0?qw:(which==1?kw:vw);
    const void* Bs = which==0?qb0:(which==1?kb0:vb0);
    float s = LD(Bs,n,md);
    for(int d=0;d<16;d++){
      float tv = sinf((float)t*LD(tw,d,md) + LD(tb,d,md));
      s += tv * LD(W,(size_t)(128+d)*128+n,md);
    }
    float* dst = which==0?qbf:(which==1?kbf:vbf);
    dst[t*128+n]=s; return;
  }
  id -= 4608;
  if(id < 256){   // GCN biases to fp32
    if(id<128) b1f[id] = LD(b1,id,md);
    else       b2f[id-128] = LD(b2,id-128,md);
    return;
  }
}

// COALESCED edge scan: one wave per row, lane i + iter u reads vector index
// u*64+i -> consecutive lanes touch consecutive 16B (1KB/wave-instruction).
__device__ __forceinline__ void dev_edges_item(int id, int md,
    const void* A, const int* inv, int* cnt, int* edges){
  int lane = id & 63; int row = id >> 6;          // row = t*MM + j (orig)
  int t = row / MM;
  int jc = inv[row];
  if(jc < 0) return;                              // inactive source
  const int* invt = inv + (size_t)t*MM;
  int* cb = cnt + (size_t)t*MM;
  int* eb = edges + (size_t)t*MM*CAP;
  if(md){   // fp32 adjacency: 512 float4 per row
    const float4* p4 = (const float4*)((const float*)A + (size_t)row*MM);
    #pragma unroll
    for(int u=0;u<8;u++){
      float4 v = p4[u*64 + lane];
      float wd[4]={v.x,v.y,v.z,v.w};
      #pragma unroll
      for(int q=0;q<4;q++){
        if(wd[q]!=0.f){
          int ibc = invt[(u*64 + lane)*4 + q];
          if(ibc >= 0){ int s=atomicAdd(&cb[ibc],1); if(s<CAP) eb[(size_t)ibc*CAP+s]=jc; }
        }
      }
    }
  } else {    // bf16 adjacency: 256 uint4 per row (8 bf16 each)
    const uint4* p4 = (const uint4*)((const unsigned short*)A + (size_t)row*MM);
    #pragma unroll
    for(int u=0;u<4;u++){
      uint4 v = p4[u*64 + lane];
      unsigned wd[4]={v.x,v.y,v.z,v.w};
      #pragma unroll
      for(int q=0;q<4;q++){
        int ib = (u*64 + lane)*8 + q*2;
        if(wd[q] & 0xFFFFu){
          int ibc = invt[ib];
          if(ibc >= 0){ int s=atomicAdd(&cb[ibc],1); if(s<CAP) eb[(size_t)ibc*CAP+s]=jc; }
        }
        if(wd[q] >> 16){
          int ibc = invt[ib+1];
          if(ibc >= 0){ int s=atomicAdd(&cb[ibc],1); if(s<CAP) eb[(size_t)ibc*CAP+s]=jc; }
        }
      }
    }
  }
}

// gemm_x reading w1 DIRECTLY (transposed access; w1 is 32KB, L2-hot)
__device__ __forceinline__ void dev_gemm_x_direct(int tileIdx, int md, int tid,
    const void* x, const int* nact, const int* aidx,
    const void* w1, float* g)
{
  const int tile = tileIdx*64;
  const int t = tile / MM, il = tile % MM;
  const int na = nact[t];
  if(il >= ((na+63)&~63)) return;
  const int wv=tid>>6, lane=tid&63, l15=lane&15, quad=lane>>4;
  const int r0 = tile + (wv>>1)*32;          // global compact row base
  const int c0 = (wv&1)*64;
  short8 bf[2][4];
  #pragma unroll
  for(int kk=0;kk<2;kk++)
    #pragma unroll
    for(int nt=0;nt<4;nt++){
      const int col = c0+nt*16+l15;
      short8 o;
      #pragma unroll
      for(int j=0;j<8;j++)
        o[j] = (short)f2bf(LD(w1, (size_t)(kk*32 + quad*8 + j)*DH + col, md));
      bf[kk][nt] = o;
    }
  const int il0 = (r0 % MM) + l15, il1 = (r0 % MM) + 16 + l15;
  const int n0 = aidx[(size_t)t*MM + (il0 < na ? il0 : 0)];
  const int n1 = aidx[(size_t)t*MM + (il1 < na ? il1 : 0)];
  const size_t xb0 = ((size_t)t*MM + n0)*DIN;
  const size_t xb1 = ((size_t)t*MM + n1)*DIN;
  f32x4 z = {0.f,0.f,0.f,0.f};
  f32x4 acc[2][4];
  #pragma unroll
  for(int i=0;i<2;i++){ acc[i][0]=z; acc[i][1]=z; acc[i][2]=z; acc[i][3]=z; }
  #pragma unroll
  for(int kk=0;kk<2;kk++){
    short8 a0 = ldx8(x, xb0 + kk*32 + quad*8, md);
    short8 a1 = ldx8(x, xb1 + kk*32 + quad*8, md);
    #pragma unroll
    for(int nt=0;nt<4;nt++){
      acc[0][nt]=MFMA(a0,bf[kk][nt],acc[0][nt]);
      acc[1][nt]=MFMA(a1,bf[kk][nt],acc[1][nt]);
    }
  }
  #pragma unroll
  for(int mt=0;mt<2;mt++)
    #pragma unroll
    for(int nt=0;nt<4;nt++){
      int col = c0+nt*16+l15;
      #pragma unroll
      for(int r=0;r<4;r++){
        int row = r0 + mt*16 + quad*4 + r;
        g[(size_t)row*DH + col] = acc[mt][nt][r];
      }
    }
}

// ---------------- L2: prepw + edges + gemm_x in one launch ----------------
__global__ __launch_bounds__(256) void k_pex(
  const void* __restrict__ x, const void* __restrict__ A,
  const void* __restrict__ w1, const void* __restrict__ w2,
  const void* __restrict__ qw, const void* __restrict__ kw, const void* __restrict__ vw,
  const void* __restrict__ qb0, const void* __restrict__ kb0, const void* __restrict__ vb0,
  const void* __restrict__ ow, const void* __restrict__ ob,
  const void* __restrict__ fw, const void* __restrict__ fb,
  const void* __restrict__ tw, const void* __restrict__ tb,
  const void* __restrict__ b1, const void* __restrict__ b2,
  const int* __restrict__ dtf,
  const int* __restrict__ inv, int* __restrict__ cnt, int* __restrict__ edges,
  const int* __restrict__ nact, const int* __restrict__ aidx, float* __restrict__ g,
  unsigned short* __restrict__ W2t,
  unsigned short* __restrict__ Wqt, unsigned short* __restrict__ Wkt,
  unsigned short* __restrict__ Wvt, unsigned short* __restrict__ Wct,
  float* __restrict__ qbf, float* __restrict__ kbf, float* __restrict__ vbf,
  float* __restrict__ bcf, float* __restrict__ b1f, float* __restrict__ b2f)
{
  const int tid = threadIdx.x;
  const int md = *dtf;                       // produced by k_maskdet block TT
  const int b = blockIdx.x;
  if(b < PWB){
    dev_prepw2_item(b*256 + tid, md, w2, qw,kw,vw, qb0,kb0,vb0, ow,ob,fw,fb, tw,tb, b1,b2,
                    W2t, Wqt, Wkt, Wvt, Wct, qbf, kbf, vbf, bcf, b1f, b2f);
  } else if(b < PWB + TM*64/256){
    dev_edges_item((b - PWB)*256 + tid, md, A, inv, cnt, edges);
  } else {
    dev_gemm_x_direct(b - PWB - TM*64/256, md, tid, x, nact, aidx, w1, g);
  }
}

// ---------------- dense GEMM on compact rows (h -> g), KD=128 ----------------
__global__ __launch_bounds__(256) void k_gemm_h(const unsigned short* __restrict__ X,
    const unsigned short* __restrict__ Wt, float* __restrict__ g,
    const int* __restrict__ nact)
{
  const int tile = blockIdx.x*64;
  const int t = tile / MM, il = tile % MM;
  const int na = nact[t];
  if(il >= ((na+63)&~63)) return;
  const int tid=threadIdx.x, wv=tid>>6, lane=tid&63, l15=lane&15, quad=lane>>4;
  const int r0 = tile + (wv>>1)*32;
  const int c0 = (wv&1)*64;
  short8 bf[4][4];
  #pragma unroll
  for(int kk=0;kk<4;kk++)
    #pragma unroll
    for(int nt=0;nt<4;nt++)
      bf[kk][nt] = *(const short8*)(Wt + (size_t)(c0+nt*16+l15)*DH + kk*32 + quad*8);
  f32x4 z = {0.f,0.f,0.f,0.f};
  f32x4 acc[2][4];
  #pragma unroll
  for(int i=0;i<2;i++){ acc[i][0]=z; acc[i][1]=z; acc[i][2]=z; acc[i][3]=z; }
  #pragma unroll
  for(int kk=0;kk<4;kk++){
    short8 a0 = *(const short8*)(X + (size_t)(r0+l15)*DH    + kk*32 + quad*8);
    short8 a1 = *(const short8*)(X + (size_t)(r0+16+l15)*DH + kk*32 + quad*8);
    #pragma unroll
    for(int nt=0;nt<4;nt++){
      acc[0][nt]=MFMA(a0,bf[kk][nt],acc[0][nt]);
      acc[1][nt]=MFMA(a1,bf[kk][nt],acc[1][nt]);
    }
  }
  #pragma unroll
  for(int mt=0;mt<2;mt++)
    #pragma unroll
    for(int nt=0;nt<4;nt++){
      int col = c0+nt*16+l15;
      #pragma unroll
      for(int r=0;r<4;r++){
        int row = r0 + mt*16 + quad*4 + r;
        g[(size_t)row*DH + col] = acc[mt][nt][r];
      }
    }
}

// ---------------- sparse GCN aggregation on compact rows -> h (bf16) ----------------
__global__ __launch_bounds__(256) void k_gather(const float* __restrict__ g,
    const int* __restrict__ edges, const int* __restrict__ cnt,
    const int* __restrict__ nact, const float* __restrict__ bias,
    unsigned short* __restrict__ h)
{
  int wv = threadIdx.x>>6, lane = threadIdx.x&63;
  int gi = blockIdx.x*4 + wv;           // compact row, < TM
  int t = gi / MM, ic = gi % MM;
  int na = nact[t];
  if(ic >= ((na+63)&~63)) return;
  unsigned int* hp = (unsigned int*)(h + (size_t)gi*DH) + lane;
  if(ic >= na){ *hp = 0; return; }      // pad row: finite zeros
  float a0=0.f, a1=0.f;
  int cn = cnt[gi]; if(cn>CAP) cn=CAP;
  const int* eb = edges + (size_t)gi*CAP;
  #pragma unroll 2
  for(int e=0;e<cn;e++){
    int jc = eb[e];
    float nj = rsqrtf((float)cnt[(size_t)t*MM+jc] + 1.f);
    float2 gr2 = *(const float2*)(g + ((size_t)t*MM + jc)*DH + 2*lane);
    a0 += nj*gr2.x; a1 += nj*gr2.y;
  }
  float ni = rsqrtf((float)cn + 1.f);
  float2 gs2 = *(const float2*)(g + (size_t)gi*DH + 2*lane);
  float h0 = ni*(a0 + ni*gs2.x) + bias[2*lane];
  float h1 = ni*(a1 + ni*gs2.y) + bias[2*lane+1];
  h0 = h0>0.f?h0:0.f; h1 = h1>0.f?h1:0.f;
  *hp = (unsigned int)f2bf(h0) | ((unsigned int)f2bf(h1) << 16);
}

// ---------------- Q/K/V GEMMs: Q,K row-major; V written TRANSPOSED directly ----------------
__global__ __launch_bounds__(256) void k_gemm_qkv(const unsigned short* __restrict__ X,
    const unsigned short* __restrict__ Wq, const unsigned short* __restrict__ Wk,
    const unsigned short* __restrict__ Wv,
    const float* __restrict__ qb, const float* __restrict__ kb, const float* __restrict__ vb,
    unsigned short* __restrict__ Qo, unsigned short* __restrict__ Ko,
    unsigned short* __restrict__ Vtc, const int* __restrict__ nact)
{
  const int tile = blockIdx.x*64;
  const int t = tile / MM, il = tile % MM;
  const int na = nact[t];
  if(il >= ((na+63)&~63)) return;
  const int which = blockIdx.z;
  const unsigned short* Wt = which==0?Wq:(which==1?Wk:Wv);
  const float* bias = which==0?qb:(which==1?kb:vb);
  const int tid=threadIdx.x, wv=tid>>6, lane=tid&63, l15=lane&15, quad=lane>>4;
  const int r0 = tile + (wv>>1)*32;
  const int c0 = (wv&1)*64;
  short8 bf[4][4];
  #pragma unroll
  for(int kk=0;kk<4;kk++)
    #pragma unroll
    for(int nt=0;nt<4;nt++)
      bf[kk][nt] = *(const short8*)(Wt + (size_t)(c0+nt*16+l15)*DH + kk*32 + quad*8);
  f32x4 z = {0.f,0.f,0.f,0.f};
  f32x4 acc[2][4];
  #pragma unroll
  for(int i=0;i<2;i++){ acc[i][0]=z; acc[i][1]=z; acc[i][2]=z; acc[i][3]=z; }
  #pragma unroll
  for(int kk=0;kk<4;kk++){
    short8 a0 = *(const short8*)(X + (size_t)(r0+l15)*DH    + kk*32 + quad*8);
    short8 a1 = *(const short8*)(X + (size_t)(r0+16+l15)*DH + kk*32 + quad*8);
    #pragma unroll
    for(int nt=0;nt<4;nt++){
      acc[0][nt]=MFMA(a0,bf[kk][nt],acc[0][nt]);
      acc[1][nt]=MFMA(a1,bf[kk][nt],acc[1][nt]);
    }
  }
  if(which < 2){
    unsigned short* o = which==0 ? Qo : Ko;
    #pragma unroll
    for(int mt=0;mt<2;mt++)
      #pragma unroll
      for(int nt=0;nt<4;nt++){
        int col = c0+nt*16+l15;
        float bb = bias[t*DH+col];
        #pragma unroll
        for(int r=0;r<4;r++){
          int row = r0 + mt*16 + quad*4 + r;
          o[(size_t)row*DH + col] = f2bf(acc[mt][nt][r] + bb);
        }
      }
  } else {
    #pragma unroll
    for(int mt=0;mt<2;mt++)
      #pragma unroll
      for(int nt=0;nt<4;nt++){
        int col = c0+nt*16+l15;
        float bb = bias[t*DH+col];
        int node0 = il + (wv>>1)*32 + mt*16 + quad*4;   // compact local row
        short4v pk;
        #pragma unroll
        for(int r=0;r<4;r++) pk[r] = (short)f2bf(acc[mt][nt][r] + bb);
        *(short4v*)(Vtc + ((size_t)t*DH + col)*MM + node0) = pk;
      }
  }
}

// ---------------- fused attention: single pass (round-7 verified, 472.8us) ----------------
__global__ __launch_bounds__(256) void k_attn(
  const unsigned short* __restrict__ Q, const unsigned short* __restrict__ Kc,
  const unsigned short* __restrict__ Vtc, const int* __restrict__ nact,
  const int* __restrict__ aidx, const unsigned short* __restrict__ Wct,
  const float* __restrict__ bc, float* __restrict__ out)
{
  __shared__ unsigned short Kl[64][136];   // 64 keys x 128ch
  __shared__ unsigned short Vl[128][72];   // 128 ch x 64 keys
  __shared__ short Pl[4][16][72];          // per-wave P tile
  __shared__ short Al[4][16][136];         // per-wave accumulator (bf16) for projection
  const int tid=threadIdx.x, wv=tid>>6, lane=tid&63, l15=lane&15, quad=lane>>4;
  const int t = blockIdx.y;
  const int na = nact[t];
  const int qblk = blockIdx.x*64;
  if(qblk >= na) return;                 // block-uniform exit (before any barrier)
  const int qbase = qblk + wv*16;
  const float scale = 0.088388347648318447f;  // 1/sqrt(128)
  const int nkt = (na + 63) >> 6;

  short8 bq[4];
  #pragma unroll
  for(int kk=0;kk<4;kk++)
    bq[kk] = *(const short8*)(Q + ((size_t)t*MM + qbase + l15)*DH + kk*32 + quad*8);

  f32x4 zz = {0.f,0.f,0.f,0.f};
  f32x4 accPV[8];
  #pragma unroll
  for(int i=0;i<8;i++) accPV[i]=zz;
  float l_run = 0.f;

  const int srow = tid >> 2, sseg = tid & 3;   // K stage: 64 rows x 4 segs
  const int vch  = tid >> 1, vhalf = tid & 1;  // V stage: 128 ch x 2 halves

  short8 kreg[4], vreg[4];
  {  // preload tile 0 into registers
    const unsigned short* gk = Kc + ((size_t)t*MM + srow)*DH + sseg*32;
    const unsigned short* gv = Vtc + ((size_t)t*DH + vch)*MM + vhalf*32;
    #pragma unroll
    for(int j=0;j<4;j++){ kreg[j] = *(const short8*)(gk + j*8);
                          vreg[j] = *(const short8*)(gv + j*8); }
  }

  for(int kt=0; kt<nkt; kt++){
    const int key0 = kt*64;
    __syncthreads();   // previous tile fully consumed before restage
    {  // write prefetched registers to LDS
      short8* kd = (short8*)&Kl[srow][sseg*32];
      short8* vd = (short8*)&Vl[vch][vhalf*32];
      #pragma unroll
      for(int j=0;j<4;j++){ kd[j] = kreg[j]; vd[j] = vreg[j]; }
    }
    __syncthreads();
    if(kt+1 < nkt){   // issue next tile's global loads; they overlap compute below
      const int key1 = key0 + 64;
      const unsigned short* gk = Kc + ((size_t)t*MM + key1 + srow)*DH + sseg*32;
      const unsigned short* gv = Vtc + ((size_t)t*DH + vch)*MM + key1 + vhalf*32;
      #pragma unroll
      for(int j=0;j<4;j++){ kreg[j] = *(const short8*)(gk + j*8);
                            vreg[j] = *(const short8*)(gv + j*8); }
    }
    // S^T = K · Q^T from LDS
    #pragma unroll
    for(int mt=0;mt<4;mt++){
      f32x4 s = zz;
      #pragma unroll
      for(int kk=0;kk<4;kk++){
        short8 ak = *(const short8*)&Kl[mt*16+l15][kk*32 + quad*8];
        s = MFMA(ak, bq[kk], s);
      }
      short4v pk;
      #pragma unroll
      for(int r=0;r<4;r++){
        float sv = fminf(fmaxf(s[r]*scale, -15.f), 15.f);
        float valid = (key0 + mt*16 + quad*4 + r < na) ? 1.f : 0.f;
        float p = __expf(sv) * valid;
        pk[r] = (short)f2bf(p);
        l_run += bf2f((unsigned short)pk[r]);
      }
      *(short4v*)&Pl[wv][l15][mt*16 + quad*4] = pk;
    }
    // PV from LDS
    #pragma unroll
    for(int kk=0;kk<2;kk++){
      short8 ap = *(const short8*)&Pl[wv][l15][kk*32 + quad*8];
      #pragma unroll
      for(int nt=0;nt<8;nt++){
        short8 bv = *(const short8*)&Vl[nt*16+l15][kk*32 + quad*8];
        accPV[nt] = MFMA(ap, bv, accPV[nt]);
      }
    }
  }
  l_run += __shfl_xor(l_run, 16, 64);
  l_run += __shfl_xor(l_run, 32, 64);

  // per-wave projection (Al slice is wave-private; no cross-wave barrier needed)
  #pragma unroll
  for(int nt=0;nt<8;nt++)
    #pragma unroll
    for(int r=0;r<4;r++){
      float av = fminf(fmaxf(accPV[nt][r], -1e30f), 1e30f);
      Al[wv][quad*4+r][nt*16+l15] = (short)f2bf(av);
    }

  const int qc = qbase + l15;
  const bool qok = (qc < na);                // predicate loads of aidx + stores only
  const float linv = (l_run > 0.f) ? 1.f/l_run : 0.f;
  const int node = aidx[(size_t)t*MM + (qok ? qc : 0)];
  #pragma unroll
  for(int mt2=0;mt2<2;mt2++){
    f32x4 d = zz;
    #pragma unroll
    for(int kk=0;kk<4;kk++){
      short8 aw = *(const short8*)(Wct + (size_t)(mt2*16+l15)*DH + kk*32 + quad*8);
      short8 bl = *(const short8*)&Al[wv][l15][kk*32 + quad*8];
      d = MFMA(aw, bl, d);
    }
    f32x4 bcv = *(const f32x4*)(bc + mt2*16 + quad*4);
    f32x4 o4;
    #pragma unroll
    for(int r=0;r<4;r++) o4[r] = d[r]*linv + bcv[r];
    if(qok)
      *(f32x4*)(out + (size_t)node*(TT*DOUT) + (size_t)t*DOUT + mt2*16 + quad*4) = o4;
  }
}

// ================= launch: 7 kernels =================

extern "C" void kernel_launch(void* const* d_in, const int* in_sizes, int n_in,
                              void* d_out, int out_size, void* d_ws, size_t ws_size,
                              hipStream_t stream)
{
  float* outp = (float*)d_out;   // reference output dtype is float32
  static const int EXP[19] = {1572864,50331648,24576,8192,128,16384,128,16,16,
                              18432,128,18432,128,18432,128,16384,128,4096,32};
  bool ok = (n_in >= 19) && (out_size == OUTSZ);
  if(ok) for(int i=0;i<19;i++) if(in_sizes[i] != EXP[i]) { ok = false; break; }
  if(!ok){
    k_fill<<<(out_size+255)/256,256,0,stream>>>(outp, out_size, 1000.f);
    return;
  }
  const void* x   = d_in[0];
  const void* A   = d_in[1];
  const void* eg  = d_in[2];
  const void* w1  = d_in[3];
  const void* b1  = d_in[4];
  const void* w2  = d_in[5];
  const void* b2  = d_in[6];
  const void* tw  = d_in[7];
  const void* tb  = d_in[8];
  const void* qw  = d_in[9];
  const void* qb0 = d_in[10];
  const void* kw  = d_in[11];
  const void* kb0 = d_in[12];
  const void* vw  = d_in[13];
  const void* vb0 = d_in[14];
  const void* ow  = d_in[15];
  const void* ob  = d_in[16];
  const void* fw  = d_in[17];
  const void* fb  = d_in[18];

  char* w = (char*)d_ws;
  size_t off = 0;
  auto alloc = [&](size_t sz)->char*{
    char* p = w + off; off = (off + sz + 255) & ~(size_t)255; return p; };
  int*   dtf   = (int*)  alloc(4);
  int*   nactb = (int*)  alloc(TT*4);
  int*   cnt   = (int*)  alloc((size_t)TM*4);
  int*   aidx  = (int*)  alloc((size_t)TM*4);
  int*   inv   = (int*)  alloc((size_t)TM*4);
  int*   edges = (int*)  alloc((size_t)TM*CAP*4);
  float* g     = (float*)alloc((size_t)TM*DH*4);   // reused as Qb+Kb after 2nd gather
  unsigned short* h   = (unsigned short*)alloc((size_t)TM*DH*2);
  unsigned short* Vtc = (unsigned short*)alloc((size_t)TT*DH*MM*2);
  unsigned short* W2t = (unsigned short*)alloc(DH*DH*2);
  unsigned short* Wqt = (unsigned short*)alloc(DH*DH*2);
  unsigned short* Wkt = (unsigned short*)alloc(DH*DH*2);
  unsigned short* Wvt = (unsigned short*)alloc(DH*DH*2);
  unsigned short* Wct = (unsigned short*)alloc(DOUT*DH*2);
  float* qbf = (float*)alloc(TT*DH*4);
  float* kbf = (float*)alloc(TT*DH*4);
  float* vbf = (float*)alloc(TT*DH*4);
  float* bcf = (float*)alloc(DOUT*4);
  float* b1f = (float*)alloc(DH*4);
  float* b2f = (float*)alloc(DH*4);
  if(off > ws_size){
    k_fill<<<(out_size+255)/256,256,0,stream>>>(outp, out_size, 500.f);
    return;
  }

  unsigned short* Qb = (unsigned short*)g;                       // TM*DH*2 bytes
  unsigned short* Kb = (unsigned short*)((char*)g + (size_t)TM*DH*2);

  // L1: mask (deterministic per-t compaction) + x dtype detect + out zero
  k_maskdet<<<OUTSZ/256,256,0,stream>>>(eg, (const unsigned short*)x, dtf,
                                        cnt, nactb, aidx, inv, outp);
  // L2: weight prep + COALESCED edge build + gemm_x (direct w1 reads), one launch
  k_pex<<<PWB + TM*64/256 + TM/64,256,0,stream>>>(
      x, A, w1, w2, qw, kw, vw, qb0, kb0, vb0, ow, ob, fw, fb, tw, tb, b1, b2,
      dtf, inv, cnt, edges, nactb, aidx, g,
      W2t, Wqt, Wkt, Wvt, Wct, qbf, kbf, vbf, bcf, b1f, b2f);
  // L3..L6: GCN + QKV
  k_gather<<<TM/4,256,0,stream>>>(g, edges, cnt, nactb, b1f, h);
  k_gemm_h<<<TM/64,256,0,stream>>>(h, W2t, g, nactb);
  k_gather<<<TM/4,256,0,stream>>>(g, edges, cnt, nactb, b2f, h);
  k_gemm_qkv<<<dim3(TM/64,1,3),256,0,stream>>>(h, Wqt,Wkt,Wvt, qbf,kbf,vbf, Qb,Kb,Vtc, nactb);
  // L7: single-pass fused attention + projection
  k_attn<<<dim3(MM/64,TT),256,0,stream>>>(Qb, Kb, Vtc, nactb, aidx, Wct, bcf, outp);
}